// Round 1
// baseline (4859.299 us; speedup 1.0000x reference)
//
#include <hip/hip_runtime.h>
#include <math.h>

#define FIN 128
#define HID 8
#define HEADS 8
#define C1 64     // HEADS*HID
#define CLS 40
#define NSLOPE 0.2f

__device__ __forceinline__ float lrelu(float x) { return x >= 0.f ? x : NSLOPE * x; }

// float atomic max via integer punning (works for mixed signs; init must be -inf)
__device__ __forceinline__ void atomicMaxF(float* addr, float val) {
    if (val >= 0.f) atomicMax((int*)addr, __float_as_int(val));
    else            atomicMin((unsigned int*)addr, __float_as_uint(val));
}

__global__ void fillf(float* __restrict__ p, int n, float v) {
    int i = blockIdx.x * blockDim.x + threadIdx.x;
    int stride = gridDim.x * blockDim.x;
    for (; i < n; i += stride) p[i] = v;
}

// h1 = x @ W1 ; al_src[n,h] = sum_c h1*a_src ; al_dst likewise. 16 nodes/block, 4 out/thread.
__global__ __launch_bounds__(256) void gemm1_kernel(
    const float* __restrict__ x, const float* __restrict__ W1,
    const float* __restrict__ a_src, const float* __restrict__ a_dst,
    float* __restrict__ h1, float* __restrict__ alS, float* __restrict__ alD, int n) {
    __shared__ float4 Wl[FIN][C1 / 4];   // 32 KB
    __shared__ float xs[16][FIN];        // 8 KB
    int t = threadIdx.x;
    const float4* W4 = (const float4*)W1;
    for (int i = t; i < FIN * (C1 / 4); i += 256) Wl[i / (C1 / 4)][i % (C1 / 4)] = W4[i];
    int node0 = blockIdx.x * 16;
    const float4* x4 = (const float4*)(x + (size_t)node0 * FIN);
    float4* xs4 = (float4*)xs;
    for (int i = t; i < 16 * FIN / 4; i += 256) {
        int nn = node0 + i / (FIN / 4);
        float4 v = {0.f, 0.f, 0.f, 0.f};
        if (nn < n) v = x4[i];
        xs4[i] = v;
    }
    __syncthreads();
    int cg = t & 15, nl = t >> 4;
    int node = node0 + nl;
    float4 acc = {0.f, 0.f, 0.f, 0.f};
    #pragma unroll 4
    for (int k = 0; k < FIN; ++k) {
        float xv = xs[nl][k];
        float4 w = Wl[k][cg];
        acc.x += xv * w.x; acc.y += xv * w.y; acc.z += xv * w.z; acc.w += xv * w.w;
    }
    int c0 = cg * 4, head = c0 >> 3, hc = c0 & 7;
    float as = acc.x * a_src[head * HID + hc]     + acc.y * a_src[head * HID + hc + 1]
             + acc.z * a_src[head * HID + hc + 2] + acc.w * a_src[head * HID + hc + 3];
    float ad = acc.x * a_dst[head * HID + hc]     + acc.y * a_dst[head * HID + hc + 1]
             + acc.z * a_dst[head * HID + hc + 2] + acc.w * a_dst[head * HID + hc + 3];
    as += __shfl_xor(as, 1, 64);
    ad += __shfl_xor(ad, 1, 64);
    if (node < n) {
        ((float4*)h1)[(size_t)node * (C1 / 4) + cg] = acc;
        if ((cg & 1) == 0) {
            alS[node * HEADS + head] = as;
            alD[node * HEADS + head] = ad;
        }
    }
}

// h2 = x2 @ W2 (64->40), single head coefficients. 1 wave per node.
__global__ __launch_bounds__(256) void gemm2_kernel(
    const float* __restrict__ x2, const float* __restrict__ W2,
    const float* __restrict__ a_src, const float* __restrict__ a_dst,
    float* __restrict__ h2, float* __restrict__ alS, float* __restrict__ alD, int n) {
    __shared__ float Wl[C1][CLS];   // 10 KB
    int t = threadIdx.x;
    for (int i = t; i < C1 * CLS; i += 256) Wl[i / CLS][i % CLS] = W2[i];
    __syncthreads();
    int lane = t & 63, wave = t >> 6;
    int node = blockIdx.x * 4 + wave;
    bool act = (node < n) && (lane < CLS);
    float acc = 0.f;
    if (act) {
        const float* xr = x2 + (size_t)node * C1;
        #pragma unroll 8
        for (int k = 0; k < C1; ++k) acc += xr[k] * Wl[k][lane];
    }
    float as = act ? acc * a_src[lane] : 0.f;
    float ad = act ? acc * a_dst[lane] : 0.f;
    #pragma unroll
    for (int off = 1; off < 64; off <<= 1) {
        as += __shfl_xor(as, off, 64);
        ad += __shfl_xor(ad, off, 64);
    }
    if (act) h2[(size_t)node * CLS + lane] = acc;
    if (node < n && lane == 0) { alS[node] = as; alD[node] = ad; }
}

// layer1 pass A: per (edge, head) segment max of leaky_relu scores into m
__global__ void edge_max1(const int* __restrict__ ei, int E, int n,
    const float* __restrict__ alS, const float* __restrict__ alD, float* __restrict__ m) {
    int tid = blockIdx.x * blockDim.x + threadIdx.x;
    int total = (E + n) * HEADS;
    if (tid >= total) return;
    int h = tid & 7, e = tid >> 3;
    int s, d;
    if (e < E) { s = ei[e]; d = ei[E + e]; } else { s = d = e - E; }
    float el = lrelu(alS[s * HEADS + h] + alD[d * HEADS + h]);
    atomicMaxF(&m[d * HEADS + h], el);
}

// layer1 pass B: accumulate exp-weighted messages (unnormalized) + denominator
__global__ void edge_acc1(const int* __restrict__ ei, int E, int n,
    const float* __restrict__ alS, const float* __restrict__ alD,
    const float* __restrict__ m, const float* __restrict__ h1,
    float* __restrict__ den, float* __restrict__ agg) {
    int tid = blockIdx.x * blockDim.x + threadIdx.x;
    int total = (E + n) * HEADS;
    if (tid >= total) return;
    int h = tid & 7, e = tid >> 3;
    int s, d;
    if (e < E) { s = ei[e]; d = ei[E + e]; } else { s = d = e - E; }
    float el = lrelu(alS[s * HEADS + h] + alD[d * HEADS + h]);
    float ex = expf(el - m[d * HEADS + h]);
    atomicAdd(&den[d * HEADS + h], ex);
    const float* hr = h1 + (size_t)s * C1 + h * HID;
    float* orow = agg + (size_t)d * C1 + h * HID;
    #pragma unroll
    for (int c = 0; c < HID; ++c) atomicAdd(&orow[c], hr[c] * ex);
}

// layer1 finish: x2 = relu(agg/den + b1) in place
__global__ void finish1(float* __restrict__ agg, const float* __restrict__ den,
    const float* __restrict__ b1, int n) {
    int i = blockIdx.x * blockDim.x + threadIdx.x;
    if (i >= n * C1) return;
    int node = i >> 6, c = i & 63;
    float v = agg[i] / den[node * HEADS + (c >> 3)] + b1[c];
    agg[i] = v > 0.f ? v : 0.f;
}

// layer2 pass A (1 head): per edge
__global__ void edge_max2(const int* __restrict__ ei, int E, int n,
    const float* __restrict__ alS, const float* __restrict__ alD, float* __restrict__ m) {
    int e = blockIdx.x * blockDim.x + threadIdx.x;
    if (e >= E + n) return;
    int s, d;
    if (e < E) { s = ei[e]; d = ei[E + e]; } else { s = d = e - E; }
    float el = lrelu(alS[s] + alD[d]);
    atomicMaxF(&m[d], el);
}

// layer2 pass B: 8 threads/edge, 5 channels each, accumulate into d_out
__global__ void edge_acc2(const int* __restrict__ ei, int E, int n,
    const float* __restrict__ alS, const float* __restrict__ alD,
    const float* __restrict__ m, const float* __restrict__ h2,
    float* __restrict__ den, float* __restrict__ out) {
    int tid = blockIdx.x * blockDim.x + threadIdx.x;
    int total = (E + n) * 8;
    if (tid >= total) return;
    int j = tid & 7, e = tid >> 3;
    int s, d;
    if (e < E) { s = ei[e]; d = ei[E + e]; } else { s = d = e - E; }
    float el = lrelu(alS[s] + alD[d]);
    float ex = expf(el - m[d]);
    if (j == 0) atomicAdd(&den[d], ex);
    const float* hr = h2 + (size_t)s * CLS + j * 5;
    float* orow = out + (size_t)d * CLS + j * 5;
    #pragma unroll
    for (int c = 0; c < 5; ++c) atomicAdd(&orow[c], hr[c] * ex);
}

// layer2 finish: normalize + bias + log_softmax, in place on d_out. 1 wave/node.
__global__ __launch_bounds__(256) void finish2(float* __restrict__ out,
    const float* __restrict__ den, const float* __restrict__ b2, int n) {
    int lane = threadIdx.x & 63, wave = threadIdx.x >> 6;
    int node = blockIdx.x * 4 + wave;
    if (node >= n) return;
    float v = -__builtin_inff();
    if (lane < CLS) v = out[(size_t)node * CLS + lane] / den[node] + b2[lane];
    float mx = v;
    #pragma unroll
    for (int off = 1; off < 64; off <<= 1) mx = fmaxf(mx, __shfl_xor(mx, off, 64));
    float ev = (lane < CLS) ? expf(v - mx) : 0.f;
    float sum = ev;
    #pragma unroll
    for (int off = 1; off < 64; off <<= 1) sum += __shfl_xor(sum, off, 64);
    float lse = mx + logf(sum);
    if (lane < CLS) out[(size_t)node * CLS + lane] = v - lse;
}

extern "C" void kernel_launch(void* const* d_in, const int* in_sizes, int n_in,
                              void* d_out, int out_size, void* d_ws, size_t ws_size,
                              hipStream_t stream) {
    const float* x   = (const float*)d_in[0];
    const int*   ei  = (const int*)d_in[1];
    const float* W1  = (const float*)d_in[2];
    const float* aS1 = (const float*)d_in[3];
    const float* aD1 = (const float*)d_in[4];
    const float* b1  = (const float*)d_in[5];
    const float* W2  = (const float*)d_in[6];
    const float* aS2 = (const float*)d_in[7];
    const float* aD2 = (const float*)d_in[8];
    const float* b2  = (const float*)d_in[9];
    float* out = (float*)d_out;

    int n = in_sizes[0] / FIN;   // 100000
    int E = in_sizes[1] / 2;     // 1600000

    // workspace layout (floats): h1[n*64] | agg[n*64] | alS[n*8] | alD[n*8] | m[n*8] | den[n*8]
    // layer 2 reuses: h2 = h1 slot (n*40), alS/alD/m/den first n entries. Total 64 MB.
    float* ws  = (float*)d_ws;
    float* h1  = ws;
    float* agg = h1 + (size_t)n * C1;
    float* alS = agg + (size_t)n * C1;
    float* alD = alS + (size_t)n * HEADS;
    float* m   = alD + (size_t)n * HEADS;
    float* den = m + (size_t)n * HEADS;

    const int T = 256;

    // ---- layer 1 ----
    fillf<<<2048, T, 0, stream>>>(m, n * HEADS, -__builtin_inff());
    fillf<<<2048, T, 0, stream>>>(den, n * HEADS, 0.f);
    fillf<<<2048, T, 0, stream>>>(agg, n * C1, 0.f);
    fillf<<<2048, T, 0, stream>>>(out, n * CLS, 0.f);

    gemm1_kernel<<<(n + 15) / 16, T, 0, stream>>>(x, W1, aS1, aD1, h1, alS, alD, n);
    int tot1 = (E + n) * HEADS;
    edge_max1<<<(tot1 + T - 1) / T, T, 0, stream>>>(ei, E, n, alS, alD, m);
    edge_acc1<<<(tot1 + T - 1) / T, T, 0, stream>>>(ei, E, n, alS, alD, m, h1, den, agg);
    finish1<<<(n * C1 + T - 1) / T, T, 0, stream>>>(agg, den, b1, n);

    // ---- layer 2 ----
    gemm2_kernel<<<(n + 3) / 4, T, 0, stream>>>(agg, W2, aS2, aD2, h1, alS, alD, n);
    fillf<<<2048, T, 0, stream>>>(m, n, -__builtin_inff());
    fillf<<<2048, T, 0, stream>>>(den, n, 0.f);
    int tot2 = E + n;
    edge_max2<<<(tot2 + T - 1) / T, T, 0, stream>>>(ei, E, n, alS, alD, m);
    edge_acc2<<<(tot1 + T - 1) / T, T, 0, stream>>>(ei, E, n, alS, alD, m, h1, den, out);
    finish2<<<(n + 3) / 4, T, 0, stream>>>(out, den, b2, n);
}

// Round 2
// 674.507 us; speedup vs baseline: 7.2042x; 7.2042x over previous
//
#include <hip/hip_runtime.h>
#include <math.h>

#define FIN 128
#define HID 8
#define HEADS 8
#define C1 64     // HEADS*HID
#define CLS 40
#define NSLOPE 0.2f
#define NINF (-__builtin_inff())

__device__ __forceinline__ float lrelu(float x) { return x >= 0.f ? x : NSLOPE * x; }

__global__ void fillI(int* __restrict__ p, int n, int v) {
    int i = blockIdx.x * blockDim.x + threadIdx.x;
    int st = gridDim.x * blockDim.x;
    for (; i < n; i += st) p[i] = v;
}

// ---- CSR build (by destination), self-loops appended as edges E..E+n-1 ----
__global__ void k_deg(const int* __restrict__ ei, int E, int n, int* __restrict__ deg) {
    int e = blockIdx.x * blockDim.x + threadIdx.x;
    if (e >= E + n) return;
    int d = (e < E) ? ei[E + e] : e - E;
    atomicAdd(&deg[d], 1);
}

__global__ __launch_bounds__(256) void k_scan1(const int* __restrict__ deg,
    int* __restrict__ rowstart, int* __restrict__ bsum, int n) {
    __shared__ int sm[256];
    int t = threadIdx.x, i = blockIdx.x * 256 + t;
    int v = (i < n) ? deg[i] : 0;
    sm[t] = v; __syncthreads();
    int x = v;
    for (int off = 1; off < 256; off <<= 1) {
        int tv = (t >= off) ? sm[t - off] : 0;
        __syncthreads();
        x += tv; sm[t] = x; __syncthreads();
    }
    if (i < n) rowstart[i] = x - v;         // exclusive within block
    if (t == 255) bsum[blockIdx.x] = x;     // block total
}

__global__ __launch_bounds__(512) void k_scan2(int* __restrict__ bsum, int nb) {
    __shared__ int sm[512];
    int t = threadIdx.x;
    int v = (t < nb) ? bsum[t] : 0;
    sm[t] = v; __syncthreads();
    int x = v;
    for (int off = 1; off < 512; off <<= 1) {
        int tv = (t >= off) ? sm[t - off] : 0;
        __syncthreads();
        x += tv; sm[t] = x; __syncthreads();
    }
    if (t < nb) bsum[t] = x - v;            // exclusive block offsets
}

__global__ void k_scan3(int* __restrict__ rowstart, const int* __restrict__ bsum,
                        int n, int total) {
    int i = blockIdx.x * blockDim.x + threadIdx.x;
    if (i < n) rowstart[i] += bsum[i >> 8];
    if (i == 0) rowstart[n] = total;
}

__global__ void k_scatter(const int* __restrict__ ei, int E, int n,
    const int* __restrict__ rowstart, int* __restrict__ cursor, int* __restrict__ csr) {
    int e = blockIdx.x * blockDim.x + threadIdx.x;
    if (e >= E + n) return;
    int s, d;
    if (e < E) { s = ei[e]; d = ei[E + e]; } else { s = d = e - E; }
    int pos = rowstart[d] + atomicAdd(&cursor[d], 1);
    csr[pos] = s;
}

// ---- layer GEMMs (unchanged from round 1, both verified) ----
__global__ __launch_bounds__(256) void gemm1_kernel(
    const float* __restrict__ x, const float* __restrict__ W1,
    const float* __restrict__ a_src, const float* __restrict__ a_dst,
    float* __restrict__ h1, float* __restrict__ alS, float* __restrict__ alD, int n) {
    __shared__ float4 Wl[FIN][C1 / 4];
    __shared__ float xs[16][FIN];
    int t = threadIdx.x;
    const float4* W4 = (const float4*)W1;
    for (int i = t; i < FIN * (C1 / 4); i += 256) Wl[i / (C1 / 4)][i % (C1 / 4)] = W4[i];
    int node0 = blockIdx.x * 16;
    const float4* x4 = (const float4*)(x + (size_t)node0 * FIN);
    float4* xs4 = (float4*)xs;
    for (int i = t; i < 16 * FIN / 4; i += 256) {
        int nn = node0 + i / (FIN / 4);
        float4 v = {0.f, 0.f, 0.f, 0.f};
        if (nn < n) v = x4[i];
        xs4[i] = v;
    }
    __syncthreads();
    int cg = t & 15, nl = t >> 4;
    int node = node0 + nl;
    float4 acc = {0.f, 0.f, 0.f, 0.f};
    #pragma unroll 4
    for (int k = 0; k < FIN; ++k) {
        float xv = xs[nl][k];
        float4 w = Wl[k][cg];
        acc.x += xv * w.x; acc.y += xv * w.y; acc.z += xv * w.z; acc.w += xv * w.w;
    }
    int c0 = cg * 4, head = c0 >> 3, hc = c0 & 7;
    float as = acc.x * a_src[head * HID + hc]     + acc.y * a_src[head * HID + hc + 1]
             + acc.z * a_src[head * HID + hc + 2] + acc.w * a_src[head * HID + hc + 3];
    float ad = acc.x * a_dst[head * HID + hc]     + acc.y * a_dst[head * HID + hc + 1]
             + acc.z * a_dst[head * HID + hc + 2] + acc.w * a_dst[head * HID + hc + 3];
    as += __shfl_xor(as, 1, 64);
    ad += __shfl_xor(ad, 1, 64);
    if (node < n) {
        ((float4*)h1)[(size_t)node * (C1 / 4) + cg] = acc;
        if ((cg & 1) == 0) {
            alS[node * HEADS + head] = as;
            alD[node * HEADS + head] = ad;
        }
    }
}

__global__ __launch_bounds__(256) void gemm2_kernel(
    const float* __restrict__ x2, const float* __restrict__ W2,
    const float* __restrict__ a_src, const float* __restrict__ a_dst,
    float* __restrict__ h2, float* __restrict__ alS, float* __restrict__ alD, int n) {
    __shared__ float Wl[C1][CLS];
    int t = threadIdx.x;
    for (int i = t; i < C1 * CLS; i += 256) Wl[i / CLS][i % CLS] = W2[i];
    __syncthreads();
    int lane = t & 63, wave = t >> 6;
    int node = blockIdx.x * 4 + wave;
    bool act = (node < n) && (lane < CLS);
    float acc = 0.f;
    if (act) {
        const float* xr = x2 + (size_t)node * C1;
        #pragma unroll 8
        for (int k = 0; k < C1; ++k) acc += xr[k] * Wl[k][lane];
    }
    float as = act ? acc * a_src[lane] : 0.f;
    float ad = act ? acc * a_dst[lane] : 0.f;
    #pragma unroll
    for (int off = 1; off < 64; off <<= 1) {
        as += __shfl_xor(as, off, 64);
        ad += __shfl_xor(ad, off, 64);
    }
    if (act) h2[(size_t)node * CLS + lane] = acc;
    if (node < n && lane == 0) { alS[node] = as; alD[node] = ad; }
}

// ---- layer 1 gather-aggregate: 1 wave per dst node, lane = channel,
//      online softmax in registers, fused bias+relu ----
__global__ __launch_bounds__(256) void k_agg1(
    const int* __restrict__ csr, const int* __restrict__ rowstart,
    const float* __restrict__ alS, const float* __restrict__ alD,
    const float* __restrict__ h1, const float* __restrict__ b1,
    float* __restrict__ x2, int n) {
    int lane = threadIdx.x & 63, wave = threadIdx.x >> 6;
    int d = blockIdx.x * 4 + wave;
    if (d >= n) return;
    int h = lane >> 3;
    float ad = alD[d * HEADS + h];
    int base = rowstart[d], cnt = rowstart[d + 1] - base;
    float m = NINF, den = 0.f, acc = 0.f;
    int s = csr[base];
    for (int j = 0; j < cnt; ++j) {
        int sn = (j + 1 < cnt) ? csr[base + j + 1] : 0;
        float sc = lrelu(alS[s * HEADS + h] + ad);
        float hv = h1[(size_t)s * C1 + lane];
        float nm = fmaxf(m, sc);
        float scale = __expf(m - nm);     // 1 when max unchanged, 0 on first edge
        float p = __expf(sc - nm);
        acc = acc * scale + p * hv;
        den = den * scale + p;
        m = nm;
        s = sn;
    }
    float v = acc / den + b1[lane];
    x2[(size_t)d * C1 + lane] = v > 0.f ? v : 0.f;
}

// ---- layer 2 gather-aggregate: 1 wave per dst node, fused bias ----
__global__ __launch_bounds__(256) void k_agg2(
    const int* __restrict__ csr, const int* __restrict__ rowstart,
    const float* __restrict__ alS, const float* __restrict__ alD,
    const float* __restrict__ h2, const float* __restrict__ b2,
    float* __restrict__ o2, int n) {
    int lane = threadIdx.x & 63, wave = threadIdx.x >> 6;
    int d = blockIdx.x * 4 + wave;
    if (d >= n) return;
    float ad = alD[d];
    int base = rowstart[d], cnt = rowstart[d + 1] - base;
    float m = NINF, den = 0.f, acc = 0.f;
    int s = csr[base];
    bool act = lane < CLS;
    for (int j = 0; j < cnt; ++j) {
        int sn = (j + 1 < cnt) ? csr[base + j + 1] : 0;
        float sc = lrelu(alS[s] + ad);
        float hv = act ? h2[(size_t)s * CLS + lane] : 0.f;
        float nm = fmaxf(m, sc);
        float scale = __expf(m - nm);
        float p = __expf(sc - nm);
        acc = acc * scale + p * hv;
        den = den * scale + p;
        m = nm;
        s = sn;
    }
    if (act) o2[(size_t)d * CLS + lane] = acc / den + b2[lane];
}

// ---- final: log_softmax over 40 classes, 1 wave per node ----
__global__ __launch_bounds__(256) void k_finish2(const float* __restrict__ o2,
    float* __restrict__ out, int n) {
    int lane = threadIdx.x & 63, wave = threadIdx.x >> 6;
    int node = blockIdx.x * 4 + wave;
    if (node >= n) return;
    float v = (lane < CLS) ? o2[(size_t)node * CLS + lane] : NINF;
    float mx = v;
    #pragma unroll
    for (int off = 1; off < 64; off <<= 1) mx = fmaxf(mx, __shfl_xor(mx, off, 64));
    float ev = (lane < CLS) ? __expf(v - mx) : 0.f;
    float sum = ev;
    #pragma unroll
    for (int off = 1; off < 64; off <<= 1) sum += __shfl_xor(sum, off, 64);
    float lse = mx + __logf(sum);
    if (lane < CLS) out[(size_t)node * CLS + lane] = v - lse;
}

extern "C" void kernel_launch(void* const* d_in, const int* in_sizes, int n_in,
                              void* d_out, int out_size, void* d_ws, size_t ws_size,
                              hipStream_t stream) {
    const float* x   = (const float*)d_in[0];
    const int*   ei  = (const int*)d_in[1];
    const float* W1  = (const float*)d_in[2];
    const float* aS1 = (const float*)d_in[3];
    const float* aD1 = (const float*)d_in[4];
    const float* b1  = (const float*)d_in[5];
    const float* W2  = (const float*)d_in[6];
    const float* aS2 = (const float*)d_in[7];
    const float* aD2 = (const float*)d_in[8];
    const float* b2  = (const float*)d_in[9];
    float* out = (float*)d_out;

    int n = in_sizes[0] / FIN;   // 100000
    int E = in_sizes[1] / 2;     // 1600000
    int En = E + n;

    // ws: h1[n*64] (reused as h2[n*40]) | x2[n*64] (reused as o2[n*40]) |
    //     alS[n*8] | alD[n*8]  -> 57.6 MB
    float* ws  = (float*)d_ws;
    float* h1  = ws;
    float* x2  = h1 + (size_t)n * C1;
    float* alS = x2 + (size_t)n * C1;
    float* alD = alS + (size_t)n * HEADS;

    // graph scratch lives in d_out (16 MB); fully overwritten by k_finish2 at
    // the end (k_agg2 writes to ws, so no read/write race on d_out).
    int* csr      = (int*)d_out;        // En
    int* rowstart = csr + En;           // n+1
    int* degcur   = rowstart + n + 1;   // n (degree, then re-zeroed as cursor)
    int* bsum     = degcur + n;         // up to 512

    const int T = 256;
    int nb = (n + 255) / 256;           // 391 <= 512
    int gE = (En + T - 1) / T;

    // ---- CSR build ----
    fillI<<<nb, T, 0, stream>>>(degcur, n, 0);
    k_deg<<<gE, T, 0, stream>>>(ei, E, n, degcur);
    k_scan1<<<nb, T, 0, stream>>>(degcur, rowstart, bsum, n);
    k_scan2<<<1, 512, 0, stream>>>(bsum, nb);
    k_scan3<<<nb, T, 0, stream>>>(rowstart, bsum, n, En);
    fillI<<<nb, T, 0, stream>>>(degcur, n, 0);
    k_scatter<<<gE, T, 0, stream>>>(ei, E, n, rowstart, degcur, csr);

    // ---- layer 1 ----
    gemm1_kernel<<<(n + 15) / 16, T, 0, stream>>>(x, W1, aS1, aD1, h1, alS, alD, n);
    k_agg1<<<(n + 3) / 4, T, 0, stream>>>(csr, rowstart, alS, alD, h1, b1, x2, n);

    // ---- layer 2 (h2 reuses h1 slot, o2 reuses x2 slot) ----
    gemm2_kernel<<<(n + 3) / 4, T, 0, stream>>>(x2, W2, aS2, aD2, h1, alS, alD, n);
    k_agg2<<<(n + 3) / 4, T, 0, stream>>>(csr, rowstart, alS, alD, h1, b2, x2, n);
    k_finish2<<<(n + 3) / 4, T, 0, stream>>>(x2, out, n);
}

// Round 3
// 432.308 us; speedup vs baseline: 11.2404x; 1.5602x over previous
//
#include <hip/hip_runtime.h>
#include <math.h>

#define FIN 128
#define HID 8
#define HEADS 8
#define C1 64     // HEADS*HID
#define CLS 40
#define NSLOPE 0.2f
#define NINF (-__builtin_inff())

__device__ __forceinline__ float lrelu(float x) { return x >= 0.f ? x : NSLOPE * x; }

__global__ void fillI(int* __restrict__ p, int n, int v) {
    int i = blockIdx.x * blockDim.x + threadIdx.x;
    int st = gridDim.x * blockDim.x;
    for (; i < n; i += st) p[i] = v;
}

// ---- CSR build (by destination), self-loops appended as edges E..E+n-1 ----
__global__ void k_deg(const int* __restrict__ ei, int E, int n, int* __restrict__ deg) {
    int e = blockIdx.x * blockDim.x + threadIdx.x;
    if (e >= E + n) return;
    int d = (e < E) ? ei[E + e] : e - E;
    atomicAdd(&deg[d], 1);
}

__global__ __launch_bounds__(256) void k_scan1(const int* __restrict__ deg,
    int* __restrict__ rowstart, int* __restrict__ bsum, int n) {
    __shared__ int sm[256];
    int t = threadIdx.x, i = blockIdx.x * 256 + t;
    int v = (i < n) ? deg[i] : 0;
    sm[t] = v; __syncthreads();
    int x = v;
    for (int off = 1; off < 256; off <<= 1) {
        int tv = (t >= off) ? sm[t - off] : 0;
        __syncthreads();
        x += tv; sm[t] = x; __syncthreads();
    }
    if (i < n) rowstart[i] = x - v;
    if (t == 255) bsum[blockIdx.x] = x;
}

__global__ __launch_bounds__(512) void k_scan2(int* __restrict__ bsum, int nb) {
    __shared__ int sm[512];
    int t = threadIdx.x;
    int v = (t < nb) ? bsum[t] : 0;
    sm[t] = v; __syncthreads();
    int x = v;
    for (int off = 1; off < 512; off <<= 1) {
        int tv = (t >= off) ? sm[t - off] : 0;
        __syncthreads();
        x += tv; sm[t] = x; __syncthreads();
    }
    if (t < nb) bsum[t] = x - v;
}

__global__ void k_scan3(int* __restrict__ rowstart, const int* __restrict__ bsum,
                        int n, int total) {
    int i = blockIdx.x * blockDim.x + threadIdx.x;
    if (i < n) rowstart[i] += bsum[i >> 8];
    if (i == 0) rowstart[n] = total;
}

__global__ void k_scatter(const int* __restrict__ ei, int E, int n,
    const int* __restrict__ rowstart, int* __restrict__ cursor, int* __restrict__ csr) {
    int e = blockIdx.x * blockDim.x + threadIdx.x;
    if (e >= E + n) return;
    int s, d;
    if (e < E) { s = ei[e]; d = ei[E + e]; } else { s = d = e - E; }
    int pos = rowstart[d] + atomicAdd(&cursor[d], 1);
    csr[pos] = s;
}

// ---- gemm1: 64 nodes/block, thread = 4 nodes x 4 channels (16 FMA / 32B LDS) ----
__global__ __launch_bounds__(256) void gemm1_kernel(
    const float* __restrict__ x, const float* __restrict__ W1,
    const float* __restrict__ a_src, const float* __restrict__ a_dst,
    float* __restrict__ h1, float* __restrict__ alS, float* __restrict__ alD, int n) {
    __shared__ float4 Wl[FIN][C1 / 4];      // 32 KB
    __shared__ float xs[64][FIN + 4];       // 33.8 KB, +4 pad -> 2-way (free) bank alias
    int t = threadIdx.x;
    const float4* W4 = (const float4*)W1;
    for (int i = t; i < FIN * (C1 / 4); i += 256) Wl[i / (C1 / 4)][i % (C1 / 4)] = W4[i];
    int node0 = blockIdx.x * 64;
    for (int i = t; i < 64 * (FIN / 4); i += 256) {
        int r = i / (FIN / 4), c = i % (FIN / 4);
        int nn = node0 + r;
        float4 v = {0.f, 0.f, 0.f, 0.f};
        if (nn < n) v = ((const float4*)x)[(size_t)nn * (FIN / 4) + c];
        *(float4*)&xs[r][c * 4] = v;
    }
    __syncthreads();
    int cg = t & 15, ng = t >> 4;           // ng: 4-node group
    int head = cg >> 1, hc = (cg & 1) * 4;
    float acc[4][4];
    #pragma unroll
    for (int i = 0; i < 4; ++i)
        for (int j = 0; j < 4; ++j) acc[i][j] = 0.f;
    #pragma unroll 2
    for (int k = 0; k < FIN; ++k) {
        float4 w = Wl[k][cg];
        #pragma unroll
        for (int i = 0; i < 4; ++i) {
            float xv = xs[ng * 4 + i][k];
            acc[i][0] += xv * w.x; acc[i][1] += xv * w.y;
            acc[i][2] += xv * w.z; acc[i][3] += xv * w.w;
        }
    }
    float a_s[4], a_d[4];
    #pragma unroll
    for (int j = 0; j < 4; ++j) {
        a_s[j] = a_src[head * HID + hc + j];
        a_d[j] = a_dst[head * HID + hc + j];
    }
    #pragma unroll
    for (int i = 0; i < 4; ++i) {
        int node = node0 + ng * 4 + i;
        float as = acc[i][0] * a_s[0] + acc[i][1] * a_s[1]
                 + acc[i][2] * a_s[2] + acc[i][3] * a_s[3];
        float ad = acc[i][0] * a_d[0] + acc[i][1] * a_d[1]
                 + acc[i][2] * a_d[2] + acc[i][3] * a_d[3];
        as += __shfl_xor(as, 1, 64);
        ad += __shfl_xor(ad, 1, 64);
        if (node < n) {
            float4 hv = {acc[i][0], acc[i][1], acc[i][2], acc[i][3]};
            ((float4*)h1)[(size_t)node * (C1 / 4) + cg] = hv;
            if ((cg & 1) == 0) {
                alS[node * HEADS + head] = as;
                alD[node * HEADS + head] = ad;
            }
        }
    }
}

// ---- gemm2: 64 nodes/block, LDS x2 tile, thread = 4 nodes x 4 classes (cg<10) ----
__global__ __launch_bounds__(256) void gemm2_kernel(
    const float* __restrict__ x2, const float* __restrict__ W2,
    const float* __restrict__ a_src, const float* __restrict__ a_dst,
    float* __restrict__ h2, float* __restrict__ alS, float* __restrict__ alD, int n) {
    __shared__ float Wl[C1][CLS];           // 10.2 KB (rows 160B, float4-aligned)
    __shared__ float xs[64][C1 + 4];        // 17.4 KB
    int t = threadIdx.x;
    for (int i = t; i < C1 * CLS; i += 256) Wl[i / CLS][i % CLS] = W2[i];
    int node0 = blockIdx.x * 64;
    for (int i = t; i < 64 * (C1 / 4); i += 256) {
        int r = i / (C1 / 4), c = i % (C1 / 4);
        int nn = node0 + r;
        float4 v = {0.f, 0.f, 0.f, 0.f};
        if (nn < n) v = ((const float4*)x2)[(size_t)nn * (C1 / 4) + c];
        *(float4*)&xs[r][c * 4] = v;
    }
    __syncthreads();
    int cg = t & 15, ng = t >> 4;
    bool act = cg < (CLS / 4);              // 10 groups of 4 classes
    float acc[4][4];
    #pragma unroll
    for (int i = 0; i < 4; ++i)
        for (int j = 0; j < 4; ++j) acc[i][j] = 0.f;
    if (act) {
        #pragma unroll 2
        for (int k = 0; k < C1; ++k) {
            float4 w = ((const float4*)&Wl[k][0])[cg];
            #pragma unroll
            for (int i = 0; i < 4; ++i) {
                float xv = xs[ng * 4 + i][k];
                acc[i][0] += xv * w.x; acc[i][1] += xv * w.y;
                acc[i][2] += xv * w.z; acc[i][3] += xv * w.w;
            }
        }
    }
    float a_s[4] = {0.f, 0.f, 0.f, 0.f}, a_d[4] = {0.f, 0.f, 0.f, 0.f};
    if (act) {
        #pragma unroll
        for (int j = 0; j < 4; ++j) {
            a_s[j] = a_src[cg * 4 + j];
            a_d[j] = a_dst[cg * 4 + j];
        }
    }
    #pragma unroll
    for (int i = 0; i < 4; ++i) {
        int node = node0 + ng * 4 + i;
        float as = acc[i][0] * a_s[0] + acc[i][1] * a_s[1]
                 + acc[i][2] * a_s[2] + acc[i][3] * a_s[3];
        float ad = acc[i][0] * a_d[0] + acc[i][1] * a_d[1]
                 + acc[i][2] * a_d[2] + acc[i][3] * a_d[3];
        #pragma unroll
        for (int off = 1; off < 16; off <<= 1) {    // reduce across the 16-cg group
            as += __shfl_xor(as, off, 64);
            ad += __shfl_xor(ad, off, 64);
        }
        if (node < n) {
            if (act) {
                float4 hv = {acc[i][0], acc[i][1], acc[i][2], acc[i][3]};
                ((float4*)h2)[(size_t)node * (CLS / 4) + cg] = hv;
            }
            if (cg == 0) { alS[node] = as; alD[node] = ad; }
        }
    }
}

// ---- layer 1 aggregate: 1 wave/dst, lane=channel, plain exp (no max shift),
//      4-way edge unroll for memory-level parallelism, fused bias+relu ----
__global__ __launch_bounds__(256) void k_agg1(
    const int* __restrict__ csr, const int* __restrict__ rowstart,
    const float* __restrict__ alS, const float* __restrict__ alD,
    const float* __restrict__ h1, const float* __restrict__ b1,
    float* __restrict__ x2, int n) {
    int lane = threadIdx.x & 63, wave = threadIdx.x >> 6;
    int d = blockIdx.x * 4 + wave;
    if (d >= n) return;
    int h = lane >> 3;
    float ad = alD[d * HEADS + h];
    int base = rowstart[d], cnt = rowstart[d + 1] - base;
    float den = 0.f, acc = 0.f;
    int j = 0;
    for (; j + 4 <= cnt; j += 4) {
        int s0 = csr[base + j],     s1 = csr[base + j + 1];
        int s2 = csr[base + j + 2], s3 = csr[base + j + 3];
        float c0 = alS[s0 * HEADS + h], c1 = alS[s1 * HEADS + h];
        float c2 = alS[s2 * HEADS + h], c3 = alS[s3 * HEADS + h];
        float v0 = h1[(size_t)s0 * C1 + lane], v1 = h1[(size_t)s1 * C1 + lane];
        float v2 = h1[(size_t)s2 * C1 + lane], v3 = h1[(size_t)s3 * C1 + lane];
        float p0 = __expf(lrelu(c0 + ad)), p1 = __expf(lrelu(c1 + ad));
        float p2 = __expf(lrelu(c2 + ad)), p3 = __expf(lrelu(c3 + ad));
        acc += p0 * v0 + p1 * v1 + p2 * v2 + p3 * v3;
        den += p0 + p1 + p2 + p3;
    }
    for (; j < cnt; ++j) {
        int s = csr[base + j];
        float p = __expf(lrelu(alS[s * HEADS + h] + ad));
        acc += p * h1[(size_t)s * C1 + lane];
        den += p;
    }
    float v = acc / den + b1[lane];
    x2[(size_t)d * C1 + lane] = v > 0.f ? v : 0.f;
}

// ---- layer 2 aggregate: same structure, CLS=40 active lanes ----
__global__ __launch_bounds__(256) void k_agg2(
    const int* __restrict__ csr, const int* __restrict__ rowstart,
    const float* __restrict__ alS, const float* __restrict__ alD,
    const float* __restrict__ h2, const float* __restrict__ b2,
    float* __restrict__ o2, int n) {
    int lane = threadIdx.x & 63, wave = threadIdx.x >> 6;
    int d = blockIdx.x * 4 + wave;
    if (d >= n) return;
    float ad = alD[d];
    int base = rowstart[d], cnt = rowstart[d + 1] - base;
    float den = 0.f, acc = 0.f;
    bool act = lane < CLS;
    int j = 0;
    for (; j + 4 <= cnt; j += 4) {
        int s0 = csr[base + j],     s1 = csr[base + j + 1];
        int s2 = csr[base + j + 2], s3 = csr[base + j + 3];
        float c0 = alS[s0], c1 = alS[s1], c2 = alS[s2], c3 = alS[s3];
        float v0 = act ? h2[(size_t)s0 * CLS + lane] : 0.f;
        float v1 = act ? h2[(size_t)s1 * CLS + lane] : 0.f;
        float v2 = act ? h2[(size_t)s2 * CLS + lane] : 0.f;
        float v3 = act ? h2[(size_t)s3 * CLS + lane] : 0.f;
        float p0 = __expf(lrelu(c0 + ad)), p1 = __expf(lrelu(c1 + ad));
        float p2 = __expf(lrelu(c2 + ad)), p3 = __expf(lrelu(c3 + ad));
        acc += p0 * v0 + p1 * v1 + p2 * v2 + p3 * v3;
        den += p0 + p1 + p2 + p3;
    }
    for (; j < cnt; ++j) {
        int s = csr[base + j];
        float p = __expf(lrelu(alS[s] + ad));
        acc += p * (act ? h2[(size_t)s * CLS + lane] : 0.f);
        den += p;
    }
    if (act) o2[(size_t)d * CLS + lane] = acc / den + b2[lane];
}

// ---- final: log_softmax over 40 classes, 1 wave per node ----
__global__ __launch_bounds__(256) void k_finish2(const float* __restrict__ o2,
    float* __restrict__ out, int n) {
    int lane = threadIdx.x & 63, wave = threadIdx.x >> 6;
    int node = blockIdx.x * 4 + wave;
    if (node >= n) return;
    float v = (lane < CLS) ? o2[(size_t)node * CLS + lane] : NINF;
    float mx = v;
    #pragma unroll
    for (int off = 1; off < 64; off <<= 1) mx = fmaxf(mx, __shfl_xor(mx, off, 64));
    float ev = (lane < CLS) ? __expf(v - mx) : 0.f;
    float sum = ev;
    #pragma unroll
    for (int off = 1; off < 64; off <<= 1) sum += __shfl_xor(sum, off, 64);
    float lse = mx + __logf(sum);
    if (lane < CLS) out[(size_t)node * CLS + lane] = v - lse;
}

extern "C" void kernel_launch(void* const* d_in, const int* in_sizes, int n_in,
                              void* d_out, int out_size, void* d_ws, size_t ws_size,
                              hipStream_t stream) {
    const float* x   = (const float*)d_in[0];
    const int*   ei  = (const int*)d_in[1];
    const float* W1  = (const float*)d_in[2];
    const float* aS1 = (const float*)d_in[3];
    const float* aD1 = (const float*)d_in[4];
    const float* b1  = (const float*)d_in[5];
    const float* W2  = (const float*)d_in[6];
    const float* aS2 = (const float*)d_in[7];
    const float* aD2 = (const float*)d_in[8];
    const float* b2  = (const float*)d_in[9];
    float* out = (float*)d_out;

    int n = in_sizes[0] / FIN;   // 100000
    int E = in_sizes[1] / 2;     // 1600000
    int En = E + n;

    // ws: h1[n*64] (reused as h2[n*40]) | x2[n*64] (reused as o2[n*40]) |
    //     alS[n*8] | alD[n*8]  -> 57.6 MB
    float* ws  = (float*)d_ws;
    float* h1  = ws;
    float* x2  = h1 + (size_t)n * C1;
    float* alS = x2 + (size_t)n * C1;
    float* alD = alS + (size_t)n * HEADS;

    // graph scratch lives in d_out (16 MB); fully overwritten by k_finish2 at
    // the end (k_agg2 writes to ws, so no read/write race on d_out).
    int* csr      = (int*)d_out;        // En
    int* rowstart = csr + En;           // n+1
    int* degcur   = rowstart + n + 1;   // n
    int* bsum     = degcur + n;         // up to 512

    const int T = 256;
    int nb = (n + 255) / 256;
    int gE = (En + T - 1) / T;

    // ---- CSR build ----
    fillI<<<nb, T, 0, stream>>>(degcur, n, 0);
    k_deg<<<gE, T, 0, stream>>>(ei, E, n, degcur);
    k_scan1<<<nb, T, 0, stream>>>(degcur, rowstart, bsum, n);
    k_scan2<<<1, 512, 0, stream>>>(bsum, nb);
    k_scan3<<<nb, T, 0, stream>>>(rowstart, bsum, n, En);
    fillI<<<nb, T, 0, stream>>>(degcur, n, 0);
    k_scatter<<<gE, T, 0, stream>>>(ei, E, n, rowstart, degcur, csr);

    // ---- layer 1 ----
    gemm1_kernel<<<(n + 63) / 64, T, 0, stream>>>(x, W1, aS1, aD1, h1, alS, alD, n);
    k_agg1<<<(n + 3) / 4, T, 0, stream>>>(csr, rowstart, alS, alD, h1, b1, x2, n);

    // ---- layer 2 (h2 reuses h1 slot, o2 reuses x2 slot) ----
    gemm2_kernel<<<(n + 63) / 64, T, 0, stream>>>(x2, W2, aS2, aD2, h1, alS, alD, n);
    k_agg2<<<(n + 3) / 4, T, 0, stream>>>(csr, rowstart, alS, alD, h1, b2, x2, n);
    k_finish2<<<(n + 3) / 4, T, 0, stream>>>(x2, out, n);
}

// Round 5
// 419.713 us; speedup vs baseline: 11.5777x; 1.0300x over previous
//
#include <hip/hip_runtime.h>
#include <hip/hip_bf16.h>
#include <math.h>

#define FIN 128
#define HID 8
#define HEADS 8
#define C1 64     // HEADS*HID
#define CLS 40
#define NSLOPE 0.2f
#define NINF (-__builtin_inff())

typedef __hip_bfloat16 bf16;

__device__ __forceinline__ float lrelu(float x) { return x >= 0.f ? x : NSLOPE * x; }

__global__ void fillI(int* __restrict__ p, int n, int v) {
    int i = blockIdx.x * blockDim.x + threadIdx.x;
    int st = gridDim.x * blockDim.x;
    for (; i < n; i += st) p[i] = v;
}

// ---- degree of real edges only (self-loops folded as +1 in scan) ----
__global__ void k_deg(const int* __restrict__ ei, int E, int* __restrict__ deg) {
    int idx = blockIdx.x * blockDim.x + threadIdx.x;   // int4 index
    int e0 = idx * 4;
    if (e0 + 3 < E) {
        int4 dv = ((const int4*)(ei + E))[idx];
        atomicAdd(&deg[dv.x], 1); atomicAdd(&deg[dv.y], 1);
        atomicAdd(&deg[dv.z], 1); atomicAdd(&deg[dv.w], 1);
    } else {
        int e_end = min(e0 + 4, E);                    // own chunk only!
        for (int e = e0; e < e_end; ++e) atomicAdd(&deg[ei[E + e]], 1);
    }
}

// exclusive scan of (deg[i]+1): block-local
__global__ __launch_bounds__(256) void k_scan1(const int* __restrict__ deg,
    int* __restrict__ rowstart, int* __restrict__ bsum, int n) {
    __shared__ int sm[256];
    int t = threadIdx.x, i = blockIdx.x * 256 + t;
    int v = (i < n) ? deg[i] + 1 : 0;
    sm[t] = v; __syncthreads();
    int x = v;
    for (int off = 1; off < 256; off <<= 1) {
        int tv = (t >= off) ? sm[t - off] : 0;
        __syncthreads();
        x += tv; sm[t] = x; __syncthreads();
    }
    if (i < n) rowstart[i] = x - v;
    if (t == 255) bsum[blockIdx.x] = x;
}

__global__ __launch_bounds__(512) void k_scan2(int* __restrict__ bsum, int nb) {
    __shared__ int sm[512];
    int t = threadIdx.x;
    int v = (t < nb) ? bsum[t] : 0;
    sm[t] = v; __syncthreads();
    int x = v;
    for (int off = 1; off < 512; off <<= 1) {
        int tv = (t >= off) ? sm[t - off] : 0;
        __syncthreads();
        x += tv; sm[t] = x; __syncthreads();
    }
    if (t < nb) bsum[t] = x - v;
}

__global__ void k_scan3(int* __restrict__ rowstart, const int* __restrict__ bsum,
                        int n, int total) {
    int i = blockIdx.x * blockDim.x + threadIdx.x;
    if (i < n) rowstart[i] += bsum[i >> 8];
    if (i == 0) rowstart[n] = total;
}

// ---- XCD-sliced scatter: group g = blockIdx&7 only writes dst in its n/8
//      slice -> csr writes stay in one XCD's L2 region. rowstart is used as
//      the cursor; after this kernel rowstart[d] == row END of d. ----
__global__ __launch_bounds__(256) void k_scatter(const int* __restrict__ ei,
    int E, int En, int n, int* __restrict__ rowcur, int* __restrict__ csr) {
    int g = blockIdx.x & 7;
    int per8 = (n + 7) >> 3;
    int lo = g * per8, hi = min(n, lo + per8);
    int idx = (blockIdx.x >> 3) * 256 + threadIdx.x;   // int4 index
    int e0 = idx * 4;
    if (e0 + 3 < E) {
        int4 dv = ((const int4*)(ei + E))[idx];
        int4 sv = ((const int4*)ei)[idx];
        if (dv.x >= lo && dv.x < hi) csr[atomicAdd(&rowcur[dv.x], 1)] = sv.x;
        if (dv.y >= lo && dv.y < hi) csr[atomicAdd(&rowcur[dv.y], 1)] = sv.y;
        if (dv.z >= lo && dv.z < hi) csr[atomicAdd(&rowcur[dv.z], 1)] = sv.z;
        if (dv.w >= lo && dv.w < hi) csr[atomicAdd(&rowcur[dv.w], 1)] = sv.w;
    } else {
        int e_end = min(e0 + 4, En);                   // own chunk only!
        for (int e = e0; e < e_end; ++e) {
            int s, d;
            if (e < E) { s = ei[e]; d = ei[E + e]; } else { s = d = e - E; }
            if (d >= lo && d < hi) csr[atomicAdd(&rowcur[d], 1)] = s;
        }
    }
}

// ---- gemm1: 64 nodes/block, thread = 4 nodes x 4 channels; bf16 h1 out ----
__global__ __launch_bounds__(256) void gemm1_kernel(
    const float* __restrict__ x, const float* __restrict__ W1,
    const float* __restrict__ a_src, const float* __restrict__ a_dst,
    bf16* __restrict__ h1b, float* __restrict__ alS, float* __restrict__ alD, int n) {
    __shared__ float4 Wl[FIN][C1 / 4];      // 32 KB
    __shared__ float xs[64][FIN + 4];       // 33.8 KB
    int t = threadIdx.x;
    const float4* W4 = (const float4*)W1;
    for (int i = t; i < FIN * (C1 / 4); i += 256) Wl[i / (C1 / 4)][i % (C1 / 4)] = W4[i];
    int node0 = blockIdx.x * 64;
    for (int i = t; i < 64 * (FIN / 4); i += 256) {
        int r = i / (FIN / 4), c = i % (FIN / 4);
        int nn = node0 + r;
        float4 v = {0.f, 0.f, 0.f, 0.f};
        if (nn < n) v = ((const float4*)x)[(size_t)nn * (FIN / 4) + c];
        *(float4*)&xs[r][c * 4] = v;
    }
    __syncthreads();
    int cg = t & 15, ng = t >> 4;
    int head = cg >> 1, hc = (cg & 1) * 4;
    float acc[4][4];
    #pragma unroll
    for (int i = 0; i < 4; ++i)
        for (int j = 0; j < 4; ++j) acc[i][j] = 0.f;
    #pragma unroll 2
    for (int k = 0; k < FIN; ++k) {
        float4 w = Wl[k][cg];
        #pragma unroll
        for (int i = 0; i < 4; ++i) {
            float xv = xs[ng * 4 + i][k];
            acc[i][0] += xv * w.x; acc[i][1] += xv * w.y;
            acc[i][2] += xv * w.z; acc[i][3] += xv * w.w;
        }
    }
    float a_s[4], a_d[4];
    #pragma unroll
    for (int j = 0; j < 4; ++j) {
        a_s[j] = a_src[head * HID + hc + j];
        a_d[j] = a_dst[head * HID + hc + j];
    }
    #pragma unroll
    for (int i = 0; i < 4; ++i) {
        int node = node0 + ng * 4 + i;
        float as = acc[i][0] * a_s[0] + acc[i][1] * a_s[1]
                 + acc[i][2] * a_s[2] + acc[i][3] * a_s[3];
        float ad = acc[i][0] * a_d[0] + acc[i][1] * a_d[1]
                 + acc[i][2] * a_d[2] + acc[i][3] * a_d[3];
        as += __shfl_xor(as, 1, 64);
        ad += __shfl_xor(ad, 1, 64);
        if (node < n) {
            union { ushort4 u; bf16 b[4]; } pk;
            #pragma unroll
            for (int j = 0; j < 4; ++j) pk.b[j] = __float2bfloat16(acc[i][j]);
            ((ushort4*)h1b)[(size_t)node * (C1 / 4) + cg] = pk.u;
            if ((cg & 1) == 0) {
                alS[node * HEADS + head] = as;
                alD[node * HEADS + head] = ad;
            }
        }
    }
}

// ---- gemm2: 64 nodes/block; bf16 h2 out ----
__global__ __launch_bounds__(256) void gemm2_kernel(
    const float* __restrict__ x2, const float* __restrict__ W2,
    const float* __restrict__ a_src, const float* __restrict__ a_dst,
    bf16* __restrict__ h2b, float* __restrict__ alS, float* __restrict__ alD, int n) {
    __shared__ float Wl[C1][CLS];
    __shared__ float xs[64][C1 + 4];
    int t = threadIdx.x;
    for (int i = t; i < C1 * CLS; i += 256) Wl[i / CLS][i % CLS] = W2[i];
    int node0 = blockIdx.x * 64;
    for (int i = t; i < 64 * (C1 / 4); i += 256) {
        int r = i / (C1 / 4), c = i % (C1 / 4);
        int nn = node0 + r;
        float4 v = {0.f, 0.f, 0.f, 0.f};
        if (nn < n) v = ((const float4*)x2)[(size_t)nn * (C1 / 4) + c];
        *(float4*)&xs[r][c * 4] = v;
    }
    __syncthreads();
    int cg = t & 15, ng = t >> 4;
    bool act = cg < (CLS / 4);
    float acc[4][4];
    #pragma unroll
    for (int i = 0; i < 4; ++i)
        for (int j = 0; j < 4; ++j) acc[i][j] = 0.f;
    if (act) {
        #pragma unroll 2
        for (int k = 0; k < C1; ++k) {
            float4 w = ((const float4*)&Wl[k][0])[cg];
            #pragma unroll
            for (int i = 0; i < 4; ++i) {
                float xv = xs[ng * 4 + i][k];
                acc[i][0] += xv * w.x; acc[i][1] += xv * w.y;
                acc[i][2] += xv * w.z; acc[i][3] += xv * w.w;
            }
        }
    }
    float a_s[4] = {0.f, 0.f, 0.f, 0.f}, a_d[4] = {0.f, 0.f, 0.f, 0.f};
    if (act) {
        #pragma unroll
        for (int j = 0; j < 4; ++j) {
            a_s[j] = a_src[cg * 4 + j];
            a_d[j] = a_dst[cg * 4 + j];
        }
    }
    #pragma unroll
    for (int i = 0; i < 4; ++i) {
        int node = node0 + ng * 4 + i;
        float as = acc[i][0] * a_s[0] + acc[i][1] * a_s[1]
                 + acc[i][2] * a_s[2] + acc[i][3] * a_s[3];
        float ad = acc[i][0] * a_d[0] + acc[i][1] * a_d[1]
                 + acc[i][2] * a_d[2] + acc[i][3] * a_d[3];
        #pragma unroll
        for (int off = 1; off < 16; off <<= 1) {
            as += __shfl_xor(as, off, 64);
            ad += __shfl_xor(ad, off, 64);
        }
        if (node < n) {
            if (act) {
                union { ushort4 u; bf16 b[4]; } pk;
                #pragma unroll
                for (int j = 0; j < 4; ++j) pk.b[j] = __float2bfloat16(acc[i][j]);
                ((ushort4*)h2b)[(size_t)node * (CLS / 4) + cg] = pk.u;
            }
            if (cg == 0) { alS[node] = as; alD[node] = ad; }
        }
    }
}

// ---- layer 1 aggregate: 1 wave/dst, lane=channel, bf16 gather,
//      plain exp (max-shift invariant), 4-way unroll, fused bias+relu ----
__global__ __launch_bounds__(256) void k_agg1(
    const int* __restrict__ csr, const int* __restrict__ rowend,
    const int* __restrict__ deg,
    const float* __restrict__ alS, const float* __restrict__ alD,
    const bf16* __restrict__ h1b, const float* __restrict__ b1,
    float* __restrict__ x2, int n) {
    int lane = threadIdx.x & 63, wave = threadIdx.x >> 6;
    int d = blockIdx.x * 4 + wave;
    if (d >= n) return;
    int h = lane >> 3;
    float ad = alD[d * HEADS + h];
    int cnt = deg[d] + 1;
    int base = rowend[d] - cnt;
    float den = 0.f, acc = 0.f;
    int j = 0;
    for (; j + 4 <= cnt; j += 4) {
        int s0 = csr[base + j],     s1 = csr[base + j + 1];
        int s2 = csr[base + j + 2], s3 = csr[base + j + 3];
        float c0 = alS[s0 * HEADS + h], c1 = alS[s1 * HEADS + h];
        float c2 = alS[s2 * HEADS + h], c3 = alS[s3 * HEADS + h];
        float v0 = __bfloat162float(h1b[(size_t)s0 * C1 + lane]);
        float v1 = __bfloat162float(h1b[(size_t)s1 * C1 + lane]);
        float v2 = __bfloat162float(h1b[(size_t)s2 * C1 + lane]);
        float v3 = __bfloat162float(h1b[(size_t)s3 * C1 + lane]);
        float p0 = __expf(lrelu(c0 + ad)), p1 = __expf(lrelu(c1 + ad));
        float p2 = __expf(lrelu(c2 + ad)), p3 = __expf(lrelu(c3 + ad));
        acc += p0 * v0 + p1 * v1 + p2 * v2 + p3 * v3;
        den += p0 + p1 + p2 + p3;
    }
    for (; j < cnt; ++j) {
        int s = csr[base + j];
        float p = __expf(lrelu(alS[s * HEADS + h] + ad));
        acc += p * __bfloat162float(h1b[(size_t)s * C1 + lane]);
        den += p;
    }
    float v = acc / den + b1[lane];
    x2[(size_t)d * C1 + lane] = v > 0.f ? v : 0.f;
}

// ---- layer 2 aggregate + fused log_softmax, writes final output ----
__global__ __launch_bounds__(256) void k_agg2(
    const int* __restrict__ csr, const int* __restrict__ rowend,
    const int* __restrict__ deg,
    const float* __restrict__ alS, const float* __restrict__ alD,
    const bf16* __restrict__ h2b, const float* __restrict__ b2,
    float* __restrict__ out, int n) {
    int lane = threadIdx.x & 63, wave = threadIdx.x >> 6;
    int d = blockIdx.x * 4 + wave;
    if (d >= n) return;
    float ad = alD[d];
    int cnt = deg[d] + 1;
    int base = rowend[d] - cnt;
    float den = 0.f, acc = 0.f;
    bool act = lane < CLS;
    int j = 0;
    for (; j + 4 <= cnt; j += 4) {
        int s0 = csr[base + j],     s1 = csr[base + j + 1];
        int s2 = csr[base + j + 2], s3 = csr[base + j + 3];
        float c0 = alS[s0], c1 = alS[s1], c2 = alS[s2], c3 = alS[s3];
        float v0 = act ? __bfloat162float(h2b[(size_t)s0 * CLS + lane]) : 0.f;
        float v1 = act ? __bfloat162float(h2b[(size_t)s1 * CLS + lane]) : 0.f;
        float v2 = act ? __bfloat162float(h2b[(size_t)s2 * CLS + lane]) : 0.f;
        float v3 = act ? __bfloat162float(h2b[(size_t)s3 * CLS + lane]) : 0.f;
        float p0 = __expf(lrelu(c0 + ad)), p1 = __expf(lrelu(c1 + ad));
        float p2 = __expf(lrelu(c2 + ad)), p3 = __expf(lrelu(c3 + ad));
        acc += p0 * v0 + p1 * v1 + p2 * v2 + p3 * v3;
        den += p0 + p1 + p2 + p3;
    }
    for (; j < cnt; ++j) {
        int s = csr[base + j];
        float p = __expf(lrelu(alS[s] + ad));
        acc += p * (act ? __bfloat162float(h2b[(size_t)s * CLS + lane]) : 0.f);
        den += p;
    }
    float v = act ? (acc / den + b2[lane]) : NINF;
    float mx = v;
    #pragma unroll
    for (int off = 1; off < 64; off <<= 1) mx = fmaxf(mx, __shfl_xor(mx, off, 64));
    float ev = act ? __expf(v - mx) : 0.f;
    float sum = ev;
    #pragma unroll
    for (int off = 1; off < 64; off <<= 1) sum += __shfl_xor(sum, off, 64);
    float lse = mx + __logf(sum);
    if (act) out[(size_t)d * CLS + lane] = v - lse;
}

extern "C" void kernel_launch(void* const* d_in, const int* in_sizes, int n_in,
                              void* d_out, int out_size, void* d_ws, size_t ws_size,
                              hipStream_t stream) {
    const float* x   = (const float*)d_in[0];
    const int*   ei  = (const int*)d_in[1];
    const float* W1  = (const float*)d_in[2];
    const float* aS1 = (const float*)d_in[3];
    const float* aD1 = (const float*)d_in[4];
    const float* b1  = (const float*)d_in[5];
    const float* W2  = (const float*)d_in[6];
    const float* aS2 = (const float*)d_in[7];
    const float* aD2 = (const float*)d_in[8];
    const float* b2  = (const float*)d_in[9];
    float* out = (float*)d_out;

    int n = in_sizes[0] / FIN;   // 100000
    int E = in_sizes[1] / 2;     // 1600000
    int En = E + n;

    // ws layout (all scratch; d_out untouched until k_agg2):
    // h1b bf16 n*64 (reused as h2b n*40) | x2 f32 n*64 | alS f32 n*8 |
    // alD f32 n*8 | csr int En | rowstart int n+1 | deg int n | bsum int 512
    // total ~52.4 MB
    char* wsb = (char*)d_ws;
    bf16*  h1b = (bf16*)wsb;
    float* x2  = (float*)(wsb + (size_t)n * C1 * 2);
    float* alS = x2 + (size_t)n * C1;
    float* alD = alS + (size_t)n * HEADS;
    int*   csr = (int*)(alD + (size_t)n * HEADS);
    int*   rowstart = csr + En;
    int*   deg = rowstart + n + 1;
    int*   bsum = deg + n;

    const int T = 256;
    int nb = (n + 255) / 256;                      // 391 (<=512)

    // ---- CSR build ----
    fillI<<<nb, T, 0, stream>>>(deg, n, 0);
    k_deg<<<(E / 4 + T - 1) / T, T, 0, stream>>>(ei, E, deg);
    k_scan1<<<nb, T, 0, stream>>>(deg, rowstart, bsum, n);
    k_scan2<<<1, 512, 0, stream>>>(bsum, nb);
    k_scan3<<<nb, T, 0, stream>>>(rowstart, bsum, n, En);
    int chunks = (En + 1023) / 1024;               // 4 edges/thread
    k_scatter<<<chunks * 8, T, 0, stream>>>(ei, E, En, n, rowstart, csr);

    // ---- layer 1 ----
    gemm1_kernel<<<(n + 63) / 64, T, 0, stream>>>(x, W1, aS1, aD1, h1b, alS, alD, n);
    k_agg1<<<(n + 3) / 4, T, 0, stream>>>(csr, rowstart, deg, alS, alD, h1b, b1, x2, n);

    // ---- layer 2 (h2b reuses h1b slot) ----
    gemm2_kernel<<<(n + 63) / 64, T, 0, stream>>>(x2, W2, aS2, aD2, h1b, alS, alD, n);
    k_agg2<<<(n + 3) / 4, T, 0, stream>>>(csr, rowstart, deg, alS, alD, h1b, b2, out, n);
}

// Round 6
// 399.335 us; speedup vs baseline: 12.1685x; 1.0510x over previous
//
#include <hip/hip_runtime.h>
#include <hip/hip_bf16.h>
#include <math.h>

#define FIN 128
#define HID 8
#define HEADS 8
#define C1 64     // HEADS*HID
#define CLS 40
#define NSLOPE 0.2f
#define NINF (-__builtin_inff())

typedef __hip_bfloat16 bf16;

__device__ __forceinline__ float lrelu(float x) { return x >= 0.f ? x : NSLOPE * x; }

// ---- degree of real edges only (self-loops folded as +1 in scan) ----
__global__ void k_deg(const int* __restrict__ ei, int E, int* __restrict__ deg) {
    int idx = blockIdx.x * blockDim.x + threadIdx.x;   // int4 index
    int e0 = idx * 4;
    if (e0 + 3 < E) {
        int4 dv = ((const int4*)(ei + E))[idx];
        atomicAdd(&deg[dv.x], 1); atomicAdd(&deg[dv.y], 1);
        atomicAdd(&deg[dv.z], 1); atomicAdd(&deg[dv.w], 1);
    } else {
        int e_end = min(e0 + 4, E);                    // own chunk only!
        for (int e = e0; e < e_end; ++e) atomicAdd(&deg[ei[E + e]], 1);
    }
}

// exclusive scan of (deg[i]+1): block-local
__global__ __launch_bounds__(256) void k_scan1(const int* __restrict__ deg,
    int* __restrict__ rowstart, int* __restrict__ bsum, int n) {
    __shared__ int sm[256];
    int t = threadIdx.x, i = blockIdx.x * 256 + t;
    int v = (i < n) ? deg[i] + 1 : 0;
    sm[t] = v; __syncthreads();
    int x = v;
    for (int off = 1; off < 256; off <<= 1) {
        int tv = (t >= off) ? sm[t - off] : 0;
        __syncthreads();
        x += tv; sm[t] = x; __syncthreads();
    }
    if (i < n) rowstart[i] = x - v;
    if (t == 255) bsum[blockIdx.x] = x;
}

__global__ __launch_bounds__(512) void k_scan2(int* __restrict__ bsum, int nb) {
    __shared__ int sm[512];
    int t = threadIdx.x;
    int v = (t < nb) ? bsum[t] : 0;
    sm[t] = v; __syncthreads();
    int x = v;
    for (int off = 1; off < 512; off <<= 1) {
        int tv = (t >= off) ? sm[t - off] : 0;
        __syncthreads();
        x += tv; sm[t] = x; __syncthreads();
    }
    if (t < nb) bsum[t] = x - v;
}

__global__ void k_scan3(int* __restrict__ rowstart, const int* __restrict__ bsum,
                        int n, int total) {
    int i = blockIdx.x * blockDim.x + threadIdx.x;
    if (i < n) rowstart[i] += bsum[i >> 8];
    if (i == 0) rowstart[n] = total;
}

// ---- XCD-sliced scatter: group g = blockIdx&7 only writes dst in its n/8
//      slice -> csr writes stay in one XCD's L2 region. rowstart is used as
//      the cursor; after this kernel rowstart[d] == row END of d. ----
__global__ __launch_bounds__(256) void k_scatter(const int* __restrict__ ei,
    int E, int En, int n, int* __restrict__ rowcur, int* __restrict__ csr) {
    int g = blockIdx.x & 7;
    int per8 = (n + 7) >> 3;
    int lo = g * per8, hi = min(n, lo + per8);
    int idx = (blockIdx.x >> 3) * 256 + threadIdx.x;   // int4 index
    int e0 = idx * 4;
    if (e0 + 3 < E) {
        int4 dv = ((const int4*)(ei + E))[idx];
        int4 sv = ((const int4*)ei)[idx];
        if (dv.x >= lo && dv.x < hi) csr[atomicAdd(&rowcur[dv.x], 1)] = sv.x;
        if (dv.y >= lo && dv.y < hi) csr[atomicAdd(&rowcur[dv.y], 1)] = sv.y;
        if (dv.z >= lo && dv.z < hi) csr[atomicAdd(&rowcur[dv.z], 1)] = sv.z;
        if (dv.w >= lo && dv.w < hi) csr[atomicAdd(&rowcur[dv.w], 1)] = sv.w;
    } else {
        int e_end = min(e0 + 4, En);                   // own chunk only!
        for (int e = e0; e < e_end; ++e) {
            int s, d;
            if (e < E) { s = ei[e]; d = ei[E + e]; } else { s = d = e - E; }
            if (d >= lo && d < hi) csr[atomicAdd(&rowcur[d], 1)] = s;
        }
    }
}

// ---- gemm1: 64 nodes/block, thread = 4 nodes x 4 channels; bf16 h1 out ----
__global__ __launch_bounds__(256) void gemm1_kernel(
    const float* __restrict__ x, const float* __restrict__ W1,
    const float* __restrict__ a_src, const float* __restrict__ a_dst,
    bf16* __restrict__ h1b, float* __restrict__ alS, float* __restrict__ alD, int n) {
    __shared__ float4 Wl[FIN][C1 / 4];      // 32 KB
    __shared__ float xs[64][FIN + 4];       // 33.8 KB
    int t = threadIdx.x;
    const float4* W4 = (const float4*)W1;
    for (int i = t; i < FIN * (C1 / 4); i += 256) Wl[i / (C1 / 4)][i % (C1 / 4)] = W4[i];
    int node0 = blockIdx.x * 64;
    for (int i = t; i < 64 * (FIN / 4); i += 256) {
        int r = i / (FIN / 4), c = i % (FIN / 4);
        int nn = node0 + r;
        float4 v = {0.f, 0.f, 0.f, 0.f};
        if (nn < n) v = ((const float4*)x)[(size_t)nn * (FIN / 4) + c];
        *(float4*)&xs[r][c * 4] = v;
    }
    __syncthreads();
    int cg = t & 15, ng = t >> 4;
    int head = cg >> 1, hc = (cg & 1) * 4;
    float acc[4][4];
    #pragma unroll
    for (int i = 0; i < 4; ++i)
        for (int j = 0; j < 4; ++j) acc[i][j] = 0.f;
    #pragma unroll 2
    for (int k = 0; k < FIN; ++k) {
        float4 w = Wl[k][cg];
        #pragma unroll
        for (int i = 0; i < 4; ++i) {
            float xv = xs[ng * 4 + i][k];
            acc[i][0] += xv * w.x; acc[i][1] += xv * w.y;
            acc[i][2] += xv * w.z; acc[i][3] += xv * w.w;
        }
    }
    float a_s[4], a_d[4];
    #pragma unroll
    for (int j = 0; j < 4; ++j) {
        a_s[j] = a_src[head * HID + hc + j];
        a_d[j] = a_dst[head * HID + hc + j];
    }
    #pragma unroll
    for (int i = 0; i < 4; ++i) {
        int node = node0 + ng * 4 + i;
        float as = acc[i][0] * a_s[0] + acc[i][1] * a_s[1]
                 + acc[i][2] * a_s[2] + acc[i][3] * a_s[3];
        float ad = acc[i][0] * a_d[0] + acc[i][1] * a_d[1]
                 + acc[i][2] * a_d[2] + acc[i][3] * a_d[3];
        as += __shfl_xor(as, 1, 64);
        ad += __shfl_xor(ad, 1, 64);
        if (node < n) {
            union { ushort4 u; bf16 b[4]; } pk;
            #pragma unroll
            for (int j = 0; j < 4; ++j) pk.b[j] = __float2bfloat16(acc[i][j]);
            ((ushort4*)h1b)[(size_t)node * (C1 / 4) + cg] = pk.u;
            if ((cg & 1) == 0) {
                alS[node * HEADS + head] = as;
                alD[node * HEADS + head] = ad;
            }
        }
    }
}

// ---- gemm2: 64 nodes/block; bf16 h2 out ----
__global__ __launch_bounds__(256) void gemm2_kernel(
    const float* __restrict__ x2, const float* __restrict__ W2,
    const float* __restrict__ a_src, const float* __restrict__ a_dst,
    bf16* __restrict__ h2b, float* __restrict__ alS, float* __restrict__ alD, int n) {
    __shared__ float Wl[C1][CLS];
    __shared__ float xs[64][C1 + 4];
    int t = threadIdx.x;
    for (int i = t; i < C1 * CLS; i += 256) Wl[i / CLS][i % CLS] = W2[i];
    int node0 = blockIdx.x * 64;
    for (int i = t; i < 64 * (C1 / 4); i += 256) {
        int r = i / (C1 / 4), c = i % (C1 / 4);
        int nn = node0 + r;
        float4 v = {0.f, 0.f, 0.f, 0.f};
        if (nn < n) v = ((const float4*)x2)[(size_t)nn * (C1 / 4) + c];
        *(float4*)&xs[r][c * 4] = v;
    }
    __syncthreads();
    int cg = t & 15, ng = t >> 4;
    bool act = cg < (CLS / 4);
    float acc[4][4];
    #pragma unroll
    for (int i = 0; i < 4; ++i)
        for (int j = 0; j < 4; ++j) acc[i][j] = 0.f;
    if (act) {
        #pragma unroll 2
        for (int k = 0; k < C1; ++k) {
            float4 w = ((const float4*)&Wl[k][0])[cg];
            #pragma unroll
            for (int i = 0; i < 4; ++i) {
                float xv = xs[ng * 4 + i][k];
                acc[i][0] += xv * w.x; acc[i][1] += xv * w.y;
                acc[i][2] += xv * w.z; acc[i][3] += xv * w.w;
            }
        }
    }
    float a_s[4] = {0.f, 0.f, 0.f, 0.f}, a_d[4] = {0.f, 0.f, 0.f, 0.f};
    if (act) {
        #pragma unroll
        for (int j = 0; j < 4; ++j) {
            a_s[j] = a_src[cg * 4 + j];
            a_d[j] = a_dst[cg * 4 + j];
        }
    }
    #pragma unroll
    for (int i = 0; i < 4; ++i) {
        int node = node0 + ng * 4 + i;
        float as = acc[i][0] * a_s[0] + acc[i][1] * a_s[1]
                 + acc[i][2] * a_s[2] + acc[i][3] * a_s[3];
        float ad = acc[i][0] * a_d[0] + acc[i][1] * a_d[1]
                 + acc[i][2] * a_d[2] + acc[i][3] * a_d[3];
        #pragma unroll
        for (int off = 1; off < 16; off <<= 1) {
            as += __shfl_xor(as, off, 64);
            ad += __shfl_xor(ad, off, 64);
        }
        if (node < n) {
            if (act) {
                union { ushort4 u; bf16 b[4]; } pk;
                #pragma unroll
                for (int j = 0; j < 4; ++j) pk.b[j] = __float2bfloat16(acc[i][j]);
                ((ushort4*)h2b)[(size_t)node * (CLS / 4) + cg] = pk.u;
            }
            if (cg == 0) { alS[node] = as; alD[node] = ad; }
        }
    }
}

// ---- layer 1 aggregate: 1 wave/dst, lane=channel, bf16 gather, plain exp,
//      scalarized row descriptors, 8/4/1 unroll ladder, fused bias+relu ----
__global__ __launch_bounds__(256) void k_agg1(
    const int* __restrict__ csr, const int* __restrict__ rowend,
    const int* __restrict__ deg,
    const float* __restrict__ alS, const float* __restrict__ alD,
    const bf16* __restrict__ h1b, const float* __restrict__ b1,
    float* __restrict__ x2, int n) {
    int lane = threadIdx.x & 63, wave = threadIdx.x >> 6;
    int d = blockIdx.x * 4 + wave;
    if (d >= n) return;
    int h = lane >> 3;
    float ad = alD[d * HEADS + h];
    int cnt  = __builtin_amdgcn_readfirstlane(deg[d]) + 1;
    int base = __builtin_amdgcn_readfirstlane(rowend[d]) - cnt;
    float den = 0.f, acc = 0.f;
    int j = 0;
    for (; j + 8 <= cnt; j += 8) {
        int s[8]; float cs[8], v[8];
        #pragma unroll
        for (int k = 0; k < 8; ++k) s[k] = csr[base + j + k];
        #pragma unroll
        for (int k = 0; k < 8; ++k) cs[k] = alS[s[k] * HEADS + h];
        #pragma unroll
        for (int k = 0; k < 8; ++k) v[k] = __bfloat162float(h1b[s[k] * C1 + lane]);
        #pragma unroll
        for (int k = 0; k < 8; ++k) {
            float p = __expf(lrelu(cs[k] + ad));
            acc = fmaf(p, v[k], acc);
            den += p;
        }
    }
    if (j + 4 <= cnt) {
        int s[4]; float cs[4], v[4];
        #pragma unroll
        for (int k = 0; k < 4; ++k) s[k] = csr[base + j + k];
        #pragma unroll
        for (int k = 0; k < 4; ++k) cs[k] = alS[s[k] * HEADS + h];
        #pragma unroll
        for (int k = 0; k < 4; ++k) v[k] = __bfloat162float(h1b[s[k] * C1 + lane]);
        #pragma unroll
        for (int k = 0; k < 4; ++k) {
            float p = __expf(lrelu(cs[k] + ad));
            acc = fmaf(p, v[k], acc);
            den += p;
        }
        j += 4;
    }
    for (; j < cnt; ++j) {
        int s = csr[base + j];
        float p = __expf(lrelu(alS[s * HEADS + h] + ad));
        acc = fmaf(p, __bfloat162float(h1b[s * C1 + lane]), acc);
        den += p;
    }
    float v = acc / den + b1[lane];
    x2[d * C1 + lane] = v > 0.f ? v : 0.f;
}

// ---- layer 2 aggregate + fused log_softmax: 320 threads = 8 groups x 40,
//      one dst per group (zero idle lanes), LDS broadcast reduce ----
__global__ __launch_bounds__(320) void k_agg2(
    const int* __restrict__ csr, const int* __restrict__ rowend,
    const int* __restrict__ deg,
    const float* __restrict__ alS, const float* __restrict__ alD,
    const bf16* __restrict__ h2b, const float* __restrict__ b2,
    float* __restrict__ out, int n) {
    __shared__ float sm[8][CLS + 4];
    int t = threadIdx.x;
    int g = t / CLS, c = t - g * CLS;
    int d = blockIdx.x * 8 + g;
    bool on = d < n;
    float ad = on ? alD[d] : 0.f;
    int cnt  = on ? deg[d] + 1 : 0;
    int base = on ? rowend[d] - cnt : 0;
    float den = 0.f, acc = 0.f;
    int j = 0;
    for (; j + 4 <= cnt; j += 4) {
        int s0 = csr[base + j],     s1 = csr[base + j + 1];
        int s2 = csr[base + j + 2], s3 = csr[base + j + 3];
        float c0 = alS[s0], c1 = alS[s1], c2 = alS[s2], c3 = alS[s3];
        float v0 = __bfloat162float(h2b[s0 * CLS + c]);
        float v1 = __bfloat162float(h2b[s1 * CLS + c]);
        float v2 = __bfloat162float(h2b[s2 * CLS + c]);
        float v3 = __bfloat162float(h2b[s3 * CLS + c]);
        float p0 = __expf(lrelu(c0 + ad)), p1 = __expf(lrelu(c1 + ad));
        float p2 = __expf(lrelu(c2 + ad)), p3 = __expf(lrelu(c3 + ad));
        acc += p0 * v0 + p1 * v1 + p2 * v2 + p3 * v3;
        den += p0 + p1 + p2 + p3;
    }
    for (; j < cnt; ++j) {
        int s = csr[base + j];
        float p = __expf(lrelu(alS[s] + ad));
        acc = fmaf(p, __bfloat162float(h2b[s * CLS + c]), acc);
        den += p;
    }
    float v = acc / den + b2[c];       // NaN for off groups (never stored)
    sm[g][c] = v;
    __syncthreads();
    float mx = NINF;
    #pragma unroll 8
    for (int k = 0; k < CLS; ++k) mx = fmaxf(mx, sm[g][k]);
    float sum = 0.f;
    #pragma unroll 8
    for (int k = 0; k < CLS; ++k) sum += __expf(sm[g][k] - mx);
    if (on) out[d * CLS + c] = v - mx - __logf(sum);
}

extern "C" void kernel_launch(void* const* d_in, const int* in_sizes, int n_in,
                              void* d_out, int out_size, void* d_ws, size_t ws_size,
                              hipStream_t stream) {
    const float* x   = (const float*)d_in[0];
    const int*   ei  = (const int*)d_in[1];
    const float* W1  = (const float*)d_in[2];
    const float* aS1 = (const float*)d_in[3];
    const float* aD1 = (const float*)d_in[4];
    const float* b1  = (const float*)d_in[5];
    const float* W2  = (const float*)d_in[6];
    const float* aS2 = (const float*)d_in[7];
    const float* aD2 = (const float*)d_in[8];
    const float* b2  = (const float*)d_in[9];
    float* out = (float*)d_out;

    int n = in_sizes[0] / FIN;   // 100000
    int E = in_sizes[1] / 2;     // 1600000
    int En = E + n;

    // ws layout (all scratch; d_out untouched until k_agg2):
    // h1b bf16 n*64 (reused as h2b n*40) | x2 f32 n*64 | alS f32 n*8 |
    // alD f32 n*8 | csr int En | rowstart int n+1 | deg int n | bsum int 512
    char* wsb = (char*)d_ws;
    bf16*  h1b = (bf16*)wsb;
    float* x2  = (float*)(wsb + (size_t)n * C1 * 2);
    float* alS = x2 + (size_t)n * C1;
    float* alD = alS + (size_t)n * HEADS;
    int*   csr = (int*)(alD + (size_t)n * HEADS);
    int*   rowstart = csr + En;
    int*   deg = rowstart + n + 1;
    int*   bsum = deg + n;

    const int T = 256;
    int nb = (n + 255) / 256;                      // 391 (<=512)

    // ---- CSR build ----
    hipMemsetAsync(deg, 0, (size_t)n * sizeof(int), stream);
    k_deg<<<(E / 4 + T - 1) / T, T, 0, stream>>>(ei, E, deg);
    k_scan1<<<nb, T, 0, stream>>>(deg, rowstart, bsum, n);
    k_scan2<<<1, 512, 0, stream>>>(bsum, nb);
    k_scan3<<<nb, T, 0, stream>>>(rowstart, bsum, n, En);
    int chunks = (En + 1023) / 1024;               // 4 edges/thread
    k_scatter<<<chunks * 8, T, 0, stream>>>(ei, E, En, n, rowstart, csr);

    // ---- layer 1 ----
    gemm1_kernel<<<(n + 63) / 64, T, 0, stream>>>(x, W1, aS1, aD1, h1b, alS, alD, n);
    k_agg1<<<(n + 3) / 4, T, 0, stream>>>(csr, rowstart, deg, alS, alD, h1b, b1, x2, n);

    // ---- layer 2 (h2b reuses h1b slot) ----
    gemm2_kernel<<<(n + 63) / 64, T, 0, stream>>>(x2, W2, aS2, aD2, h1b, alS, alD, n);
    k_agg2<<<(n + 7) / 8, 320, 0, stream>>>(csr, rowstart, deg, alS, alD, h1b, b2, out, n);
}

// Round 7
// 355.092 us; speedup vs baseline: 13.6846x; 1.1246x over previous
//
#include <hip/hip_runtime.h>
#include <hip/hip_bf16.h>
#include <math.h>

#define FIN 128
#define HID 8
#define HEADS 8
#define C1 64     // HEADS*HID
#define CLS 40
#define NSLOPE 0.2f
#define NINF (-__builtin_inff())

typedef __hip_bfloat16 bf16;

__device__ __forceinline__ float lrelu(float x) { return x >= 0.f ? x : NSLOPE * x; }

// ---- degree of real edges only (self-loops folded as +1 in scan) ----
__global__ void k_deg(const int* __restrict__ ei, int E, int* __restrict__ deg) {
    int idx = blockIdx.x * blockDim.x + threadIdx.x;   // int4 index
    int e0 = idx * 4;
    if (e0 + 3 < E) {
        int4 dv = ((const int4*)(ei + E))[idx];
        atomicAdd(&deg[dv.x], 1); atomicAdd(&deg[dv.y], 1);
        atomicAdd(&deg[dv.z], 1); atomicAdd(&deg[dv.w], 1);
    } else {
        int e_end = min(e0 + 4, E);                    // own chunk only!
        for (int e = e0; e < e_end; ++e) atomicAdd(&deg[ei[E + e]], 1);
    }
}

// exclusive scan of (deg[i]+1): block-local
__global__ __launch_bounds__(256) void k_scan1(const int* __restrict__ deg,
    int* __restrict__ rowstart, int* __restrict__ bsum, int n) {
    __shared__ int sm[256];
    int t = threadIdx.x, i = blockIdx.x * 256 + t;
    int v = (i < n) ? deg[i] + 1 : 0;
    sm[t] = v; __syncthreads();
    int x = v;
    for (int off = 1; off < 256; off <<= 1) {
        int tv = (t >= off) ? sm[t - off] : 0;
        __syncthreads();
        x += tv; sm[t] = x; __syncthreads();
    }
    if (i < n) rowstart[i] = x - v;
    if (t == 255) bsum[blockIdx.x] = x;
}

__global__ __launch_bounds__(512) void k_scan2(int* __restrict__ bsum, int nb) {
    __shared__ int sm[512];
    int t = threadIdx.x;
    int v = (t < nb) ? bsum[t] : 0;
    sm[t] = v; __syncthreads();
    int x = v;
    for (int off = 1; off < 512; off <<= 1) {
        int tv = (t >= off) ? sm[t - off] : 0;
        __syncthreads();
        x += tv; sm[t] = x; __syncthreads();
    }
    if (t < nb) bsum[t] = x - v;
}

__global__ void k_scan3(int* __restrict__ rowstart, const int* __restrict__ bsum,
                        int n, int total) {
    int i = blockIdx.x * blockDim.x + threadIdx.x;
    if (i < n) rowstart[i] += bsum[i >> 8];
    if (i == 0) rowstart[n] = total;
}

// ---- XCD-sliced scatter (rowstart becomes row END cursor) ----
__global__ __launch_bounds__(256) void k_scatter(const int* __restrict__ ei,
    int E, int En, int n, int* __restrict__ rowcur, int* __restrict__ csr) {
    int g = blockIdx.x & 7;
    int per8 = (n + 7) >> 3;
    int lo = g * per8, hi = min(n, lo + per8);
    int idx = (blockIdx.x >> 3) * 256 + threadIdx.x;   // int4 index
    int e0 = idx * 4;
    if (e0 + 3 < E) {
        int4 dv = ((const int4*)(ei + E))[idx];
        int4 sv = ((const int4*)ei)[idx];
        if (dv.x >= lo && dv.x < hi) csr[atomicAdd(&rowcur[dv.x], 1)] = sv.x;
        if (dv.y >= lo && dv.y < hi) csr[atomicAdd(&rowcur[dv.y], 1)] = sv.y;
        if (dv.z >= lo && dv.z < hi) csr[atomicAdd(&rowcur[dv.z], 1)] = sv.z;
        if (dv.w >= lo && dv.w < hi) csr[atomicAdd(&rowcur[dv.w], 1)] = sv.w;
    } else {
        int e_end = min(e0 + 4, En);                   // own chunk only!
        for (int e = e0; e < e_end; ++e) {
            int s, d;
            if (e < E) { s = ei[e]; d = ei[E + e]; } else { s = d = e - E; }
            if (d >= lo && d < hi) csr[atomicAdd(&rowcur[d], 1)] = s;
        }
    }
}

// ---- gemm1: 64 nodes/block, thread = 4 nodes x 4 channels; bf16 h1 out ----
__global__ __launch_bounds__(256) void gemm1_kernel(
    const float* __restrict__ x, const float* __restrict__ W1,
    const float* __restrict__ a_src, const float* __restrict__ a_dst,
    bf16* __restrict__ h1b, float* __restrict__ alS, float* __restrict__ alD, int n) {
    __shared__ float4 Wl[FIN][C1 / 4];      // 32 KB
    __shared__ float xs[64][FIN + 4];       // 33.8 KB
    int t = threadIdx.x;
    const float4* W4 = (const float4*)W1;
    for (int i = t; i < FIN * (C1 / 4); i += 256) Wl[i / (C1 / 4)][i % (C1 / 4)] = W4[i];
    int node0 = blockIdx.x * 64;
    for (int i = t; i < 64 * (FIN / 4); i += 256) {
        int r = i / (FIN / 4), c = i % (FIN / 4);
        int nn = node0 + r;
        float4 v = {0.f, 0.f, 0.f, 0.f};
        if (nn < n) v = ((const float4*)x)[(size_t)nn * (FIN / 4) + c];
        *(float4*)&xs[r][c * 4] = v;
    }
    __syncthreads();
    int cg = t & 15, ng = t >> 4;
    int head = cg >> 1, hc = (cg & 1) * 4;
    float acc[4][4];
    #pragma unroll
    for (int i = 0; i < 4; ++i)
        for (int j = 0; j < 4; ++j) acc[i][j] = 0.f;
    #pragma unroll 2
    for (int k = 0; k < FIN; ++k) {
        float4 w = Wl[k][cg];
        #pragma unroll
        for (int i = 0; i < 4; ++i) {
            float xv = xs[ng * 4 + i][k];
            acc[i][0] += xv * w.x; acc[i][1] += xv * w.y;
            acc[i][2] += xv * w.z; acc[i][3] += xv * w.w;
        }
    }
    float a_s[4], a_d[4];
    #pragma unroll
    for (int j = 0; j < 4; ++j) {
        a_s[j] = a_src[head * HID + hc + j];
        a_d[j] = a_dst[head * HID + hc + j];
    }
    #pragma unroll
    for (int i = 0; i < 4; ++i) {
        int node = node0 + ng * 4 + i;
        float as = acc[i][0] * a_s[0] + acc[i][1] * a_s[1]
                 + acc[i][2] * a_s[2] + acc[i][3] * a_s[3];
        float ad = acc[i][0] * a_d[0] + acc[i][1] * a_d[1]
                 + acc[i][2] * a_d[2] + acc[i][3] * a_d[3];
        as += __shfl_xor(as, 1, 64);
        ad += __shfl_xor(ad, 1, 64);
        if (node < n) {
            union { ushort4 u; bf16 b[4]; } pk;
            #pragma unroll
            for (int j = 0; j < 4; ++j) pk.b[j] = __float2bfloat16(acc[i][j]);
            ((ushort4*)h1b)[(size_t)node * (C1 / 4) + cg] = pk.u;
            if ((cg & 1) == 0) {
                alS[node * HEADS + head] = as;
                alD[node * HEADS + head] = ad;
            }
        }
    }
}

// ---- gemm2: 64 nodes/block; bf16 h2 out ----
__global__ __launch_bounds__(256) void gemm2_kernel(
    const float* __restrict__ x2, const float* __restrict__ W2,
    const float* __restrict__ a_src, const float* __restrict__ a_dst,
    bf16* __restrict__ h2b, float* __restrict__ alS, float* __restrict__ alD, int n) {
    __shared__ float Wl[C1][CLS];
    __shared__ float xs[64][C1 + 4];
    int t = threadIdx.x;
    for (int i = t; i < C1 * CLS; i += 256) Wl[i / CLS][i % CLS] = W2[i];
    int node0 = blockIdx.x * 64;
    for (int i = t; i < 64 * (C1 / 4); i += 256) {
        int r = i / (C1 / 4), c = i % (C1 / 4);
        int nn = node0 + r;
        float4 v = {0.f, 0.f, 0.f, 0.f};
        if (nn < n) v = ((const float4*)x2)[(size_t)nn * (C1 / 4) + c];
        *(float4*)&xs[r][c * 4] = v;
    }
    __syncthreads();
    int cg = t & 15, ng = t >> 4;
    bool act = cg < (CLS / 4);
    float acc[4][4];
    #pragma unroll
    for (int i = 0; i < 4; ++i)
        for (int j = 0; j < 4; ++j) acc[i][j] = 0.f;
    if (act) {
        #pragma unroll 2
        for (int k = 0; k < C1; ++k) {
            float4 w = ((const float4*)&Wl[k][0])[cg];
            #pragma unroll
            for (int i = 0; i < 4; ++i) {
                float xv = xs[ng * 4 + i][k];
                acc[i][0] += xv * w.x; acc[i][1] += xv * w.y;
                acc[i][2] += xv * w.z; acc[i][3] += xv * w.w;
            }
        }
    }
    float a_s[4] = {0.f, 0.f, 0.f, 0.f}, a_d[4] = {0.f, 0.f, 0.f, 0.f};
    if (act) {
        #pragma unroll
        for (int j = 0; j < 4; ++j) {
            a_s[j] = a_src[cg * 4 + j];
            a_d[j] = a_dst[cg * 4 + j];
        }
    }
    #pragma unroll
    for (int i = 0; i < 4; ++i) {
        int node = node0 + ng * 4 + i;
        float as = acc[i][0] * a_s[0] + acc[i][1] * a_s[1]
                 + acc[i][2] * a_s[2] + acc[i][3] * a_s[3];
        float ad = acc[i][0] * a_d[0] + acc[i][1] * a_d[1]
                 + acc[i][2] * a_d[2] + acc[i][3] * a_d[3];
        #pragma unroll
        for (int off = 1; off < 16; off <<= 1) {
            as += __shfl_xor(as, off, 64);
            ad += __shfl_xor(ad, off, 64);
        }
        if (node < n) {
            if (act) {
                union { ushort4 u; bf16 b[4]; } pk;
                #pragma unroll
                for (int j = 0; j < 4; ++j) pk.b[j] = __float2bfloat16(acc[i][j]);
                ((ushort4*)h2b)[(size_t)node * (CLS / 4) + cg] = pk.u;
            }
            if (cg == 0) { alS[node] = as; alD[node] = ad; }
        }
    }
}

// ---- layer 1 aggregate, two-phase: A) lane=edge computes 8 exps once,
//      B) lane=channel streams independent bf16 gathers. 1 wave/node. ----
__global__ __launch_bounds__(256) void k_agg1(
    const int* __restrict__ csr, const int* __restrict__ rowend,
    const int* __restrict__ deg,
    const float* __restrict__ alS, const float* __restrict__ alD,
    const bf16* __restrict__ h1b, const float* __restrict__ b1,
    float* __restrict__ x2, int n) {
    __shared__ int    ls[4][64];
    __shared__ float4 lp4[4][128];          // p[edge][8 heads], 8.2 KB
    int lane = threadIdx.x & 63, wv = threadIdx.x >> 6;
    int d = blockIdx.x * 4 + wv;
    if (d >= n) return;                     // wave-uniform
    float4 ad0 = *(const float4*)(alD + d * HEADS);
    float4 ad1 = *(const float4*)(alD + d * HEADS + 4);
    float adh[8] = {ad0.x, ad0.y, ad0.z, ad0.w, ad1.x, ad1.y, ad1.z, ad1.w};
    int cnt  = deg[d] + 1;
    int base = rowend[d] - cnt;
    int hsel = lane >> 3;
    float acc = 0.f, den = 0.f;
    const float* lpf = (const float*)&lp4[wv][0];
    for (int jb = 0; jb < cnt; jb += 64) {
        int ec = min(64, cnt - jb);
        // phase A: one edge per lane
        int jj = jb + lane;
        bool on = jj < cnt;
        int s = on ? csr[base + jj] : 0;
        ls[wv][lane] = s;
        float4 a0 = *(const float4*)(alS + s * HEADS);
        float4 a1 = *(const float4*)(alS + s * HEADS + 4);
        float av[8] = {a0.x, a0.y, a0.z, a0.w, a1.x, a1.y, a1.z, a1.w};
        float pv[8];
        #pragma unroll
        for (int h = 0; h < 8; ++h)
            pv[h] = on ? __expf(lrelu(av[h] + adh[h])) : 0.f;
        lp4[wv][lane * 2]     = make_float4(pv[0], pv[1], pv[2], pv[3]);
        lp4[wv][lane * 2 + 1] = make_float4(pv[4], pv[5], pv[6], pv[7]);
        // phase B: lane=channel, independent gathers (same-wave LDS, no barrier)
        int j = 0;
        for (; j + 4 <= ec; j += 4) {
            int s0 = ls[wv][j],     s1 = ls[wv][j + 1];
            int s2 = ls[wv][j + 2], s3 = ls[wv][j + 3];
            float p0 = lpf[(j    ) * 8 + hsel], p1 = lpf[(j + 1) * 8 + hsel];
            float p2 = lpf[(j + 2) * 8 + hsel], p3 = lpf[(j + 3) * 8 + hsel];
            float v0 = __bfloat162float(h1b[s0 * C1 + lane]);
            float v1 = __bfloat162float(h1b[s1 * C1 + lane]);
            float v2 = __bfloat162float(h1b[s2 * C1 + lane]);
            float v3 = __bfloat162float(h1b[s3 * C1 + lane]);
            acc = fmaf(p0, v0, acc); acc = fmaf(p1, v1, acc);
            acc = fmaf(p2, v2, acc); acc = fmaf(p3, v3, acc);
            den += p0 + p1 + p2 + p3;
        }
        for (; j < ec; ++j) {
            int s0 = ls[wv][j];
            float p0 = lpf[j * 8 + hsel];
            acc = fmaf(p0, __bfloat162float(h1b[s0 * C1 + lane]), acc);
            den += p0;
        }
    }
    float v = acc / den + b1[lane];
    x2[d * C1 + lane] = v > 0.f ? v : 0.f;
}

// ---- layer 2 aggregate, two-phase, + fused log_softmax. 1 wave/node. ----
__global__ __launch_bounds__(256) void k_agg2(
    const int* __restrict__ csr, const int* __restrict__ rowend,
    const int* __restrict__ deg,
    const float* __restrict__ alS, const float* __restrict__ alD,
    const bf16* __restrict__ h2b, const float* __restrict__ b2,
    float* __restrict__ out, int n) {
    __shared__ int2 lsp[4][64];             // {src, p-bits}, 2 KB
    int lane = threadIdx.x & 63, wv = threadIdx.x >> 6;
    int d = blockIdx.x * 4 + wv;
    if (d >= n) return;                     // wave-uniform
    float ad = alD[d];
    int cnt  = deg[d] + 1;
    int base = rowend[d] - cnt;
    bool act = lane < CLS;
    float acc = 0.f, den = 0.f;
    for (int jb = 0; jb < cnt; jb += 64) {
        int ec = min(64, cnt - jb);
        // phase A: one edge per lane, ONE exp per edge
        int jj = jb + lane;
        bool on = jj < cnt;
        int s = on ? csr[base + jj] : 0;
        float p = on ? __expf(lrelu(alS[s] + ad)) : 0.f;
        den += p;
        lsp[wv][lane] = make_int2(s, __float_as_int(p));
        // phase B: lane=class, exec-masked so rows fetch 80 B
        if (act) {
            int j = 0;
            for (; j + 4 <= ec; j += 4) {
                int2 e0 = lsp[wv][j],     e1 = lsp[wv][j + 1];
                int2 e2 = lsp[wv][j + 2], e3 = lsp[wv][j + 3];
                float v0 = __bfloat162float(h2b[e0.x * CLS + lane]);
                float v1 = __bfloat162float(h2b[e1.x * CLS + lane]);
                float v2 = __bfloat162float(h2b[e2.x * CLS + lane]);
                float v3 = __bfloat162float(h2b[e3.x * CLS + lane]);
                acc = fmaf(__int_as_float(e0.y), v0, acc);
                acc = fmaf(__int_as_float(e1.y), v1, acc);
                acc = fmaf(__int_as_float(e2.y), v2, acc);
                acc = fmaf(__int_as_float(e3.y), v3, acc);
            }
            for (; j < ec; ++j) {
                int2 e0 = lsp[wv][j];
                acc = fmaf(__int_as_float(e0.y),
                           __bfloat162float(h2b[e0.x * CLS + lane]), acc);
            }
        }
    }
    // den: sum of per-lane partials across the wave
    #pragma unroll
    for (int off = 1; off < 64; off <<= 1) den += __shfl_xor(den, off, 64);
    float v = act ? (acc / den + b2[lane]) : NINF;
    float mx = v;
    #pragma unroll
    for (int off = 1; off < 64; off <<= 1) mx = fmaxf(mx, __shfl_xor(mx, off, 64));
    float ev = act ? __expf(v - mx) : 0.f;
    float sum = ev;
    #pragma unroll
    for (int off = 1; off < 64; off <<= 1) sum += __shfl_xor(sum, off, 64);
    float lse = mx + __logf(sum);
    if (act) out[d * CLS + lane] = v - lse;
}

extern "C" void kernel_launch(void* const* d_in, const int* in_sizes, int n_in,
                              void* d_out, int out_size, void* d_ws, size_t ws_size,
                              hipStream_t stream) {
    const float* x   = (const float*)d_in[0];
    const int*   ei  = (const int*)d_in[1];
    const float* W1  = (const float*)d_in[2];
    const float* aS1 = (const float*)d_in[3];
    const float* aD1 = (const float*)d_in[4];
    const float* b1  = (const float*)d_in[5];
    const float* W2  = (const float*)d_in[6];
    const float* aS2 = (const float*)d_in[7];
    const float* aD2 = (const float*)d_in[8];
    const float* b2  = (const float*)d_in[9];
    float* out = (float*)d_out;

    int n = in_sizes[0] / FIN;   // 100000
    int E = in_sizes[1] / 2;     // 1600000
    int En = E + n;

    // ws layout (all scratch; d_out untouched until k_agg2):
    // h1b bf16 n*64 (reused as h2b n*40) | x2 f32 n*64 | alS f32 n*8 |
    // alD f32 n*8 | csr int En | rowstart int n+1 | deg int n | bsum int 512
    char* wsb = (char*)d_ws;
    bf16*  h1b = (bf16*)wsb;
    float* x2  = (float*)(wsb + (size_t)n * C1 * 2);
    float* alS = x2 + (size_t)n * C1;
    float* alD = alS + (size_t)n * HEADS;
    int*   csr = (int*)(alD + (size_t)n * HEADS);
    int*   rowstart = csr + En;
    int*   deg = rowstart + n + 1;
    int*   bsum = deg + n;

    const int T = 256;
    int nb = (n + 255) / 256;                      // 391 (<=512)

    // ---- CSR build ----
    hipMemsetAsync(deg, 0, (size_t)n * sizeof(int), stream);
    k_deg<<<(E / 4 + T - 1) / T, T, 0, stream>>>(ei, E, deg);
    k_scan1<<<nb, T, 0, stream>>>(deg, rowstart, bsum, n);
    k_scan2<<<1, 512, 0, stream>>>(bsum, nb);
    k_scan3<<<nb, T, 0, stream>>>(rowstart, bsum, n, En);
    int chunks = (En + 1023) / 1024;               // 4 edges/thread
    k_scatter<<<chunks * 8, T, 0, stream>>>(ei, E, En, n, rowstart, csr);

    // ---- layer 1 ----
    gemm1_kernel<<<(n + 63) / 64, T, 0, stream>>>(x, W1, aS1, aD1, h1b, alS, alD, n);
    k_agg1<<<(n + 3) / 4, T, 0, stream>>>(csr, rowstart, deg, alS, alD, h1b, b1, x2, n);

    // ---- layer 2 (h2b reuses h1b slot) ----
    gemm2_kernel<<<(n + 63) / 64, T, 0, stream>>>(x2, W2, aS2, aD2, h1b, alS, alD, n);
    k_agg2<<<(n + 3) / 4, T, 0, stream>>>(csr, rowstart, deg, alS, alD, h1b, b2, out, n);
}